// Round 3
// baseline (1078.386 us; speedup 1.0000x reference)
//
#include <hip/hip_runtime.h>

// Multiscale Residual VQ (VAR-style), MI355X gfx950.
// Round 8: dist restructured as approx-GEMM + exact-refine:
//   - k_dist1: hh-only f16 GEMM (1/3 MFMA, 1/2 LDS vs dual-split), 32KB LDS,
//     launch_bounds(256,4) -> 4 blocks/CU. Epilogue: atomicMin global approx
//     min; append all candidates with d <= min(old,blockmin)+DELTA to a per-m
//     list (CAP=16, overflow flag via cnt). Provably contains exact argmin
//     (d(n*)-gmin_now <= 2*eps_cross << DELTA=0.5).
//   - k_refine: fp64-exact dists on surviving candidates (~2-4/m), tie->lowest
//     idx; overflow fallback scans all 4096. Writes exact argmin to minbuf.
//   Result: downstream sees EXACT argmin (more accurate than round 7).
// - k_final fused into last k_conv (out = x - resid_new), -48MB traffic.
// k_phi / k_conv GEMM cores unchanged (they need values, keep dual-split).

#define ND 512
#define NCB 4096
#define CAP 16
#define DELTA 0.5f

typedef _Float16 half8v __attribute__((ext_vector_type(8)));
typedef float floatx4 __attribute__((ext_vector_type(4)));

struct HL { _Float16 h, l; };

__device__ __forceinline__ HL split2(float v) {
    HL r;
    r.h = (_Float16)v;
    r.l = (_Float16)((v - (float)r.h) * 4096.0f);
    return r;
}

__device__ __forceinline__ unsigned long long pack_dist(float d, int n) {
    unsigned u = __float_as_uint(d);
    u = (u & 0x80000000u) ? ~u : (u | 0x80000000u);   // monotone total order
    return ((unsigned long long)u << 32) | (unsigned)n; // tie -> lowest idx
}

__device__ __forceinline__ float unpack_dist(unsigned long long p) {
    unsigned u = (unsigned)(p >> 32);
    u = (u & 0x80000000u) ? (u & 0x7fffffffu) : ~u;
    return __uint_as_float(u);
}

// async global->LDS, 16B per lane; LDS dest = wave-uniform base + lane*16
__device__ __forceinline__ void gl2lds16(const _Float16* g, _Float16* l) {
    __builtin_amdgcn_global_load_lds(
        (const __attribute__((address_space(1))) unsigned int*)g,
        (__attribute__((address_space(3))) unsigned int*)l, 16, 0, 0);
}

// e_sq[c] = sum_d embed[c,d]^2, fp64 accumulate
__global__ __launch_bounds__(256) void k_esq(const float* __restrict__ embed,
                                             float* __restrict__ esq) {
    int c = blockIdx.x * 4 + (threadIdx.x >> 6);
    int lane = threadIdx.x & 63;
    const float* row = embed + (size_t)c * ND;
    double acc = 0.0;
#pragma unroll
    for (int i = 0; i < ND / 64; ++i) {
        float v = row[lane + i * 64];
        acc += (double)v * (double)v;
    }
#pragma unroll
    for (int off = 32; off > 0; off >>= 1) acc += __shfl_down(acc, off, 64);
    if (lane == 0) esq[c] = (float)acc;
}

__global__ __launch_bounds__(256) void k_copy(const float* __restrict__ src,
                                              float* __restrict__ dst) {
    int gid = blockIdx.x * 256 + threadIdx.x;
    ((float4*)dst)[gid] = ((const float4*)src)[gid];
}

// embed -> ehi/elo (4096x512 halves)
__global__ __launch_bounds__(256) void k_split_embed(const float* __restrict__ embed,
        _Float16* __restrict__ eh, _Float16* __restrict__ el) {
    int gid = blockIdx.x * 256 + threadIdx.x;       // 524288 float4s
    float4 v = ((const float4*)embed)[gid];
    HL a = split2(v.x), b = split2(v.y), c = split2(v.z), d = split2(v.w);
    _Float16* ph = eh + (size_t)gid * 4;
    _Float16* pl = el + (size_t)gid * 4;
    ph[0] = a.h; ph[1] = b.h; ph[2] = c.h; ph[3] = d.h;
    pl[0] = a.l; pl[1] = b.l; pl[2] = c.l; pl[3] = d.l;
}

// Wt2[kp][tap*512+dout][din] hi/lo from pw[kp][dout][din][tap]; output-indexed
__global__ __launch_bounds__(256) void k_split_w(const float* __restrict__ pw,
        _Float16* __restrict__ wh, _Float16* __restrict__ wl) {
    int gid = blockIdx.x * 256 + threadIdx.x;       // 4*1536*512 = 3,145,728
    int din = gid & 511;
    int nn = (gid >> 9) % 1536;
    int kp = gid / (512 * 1536);
    int tap = nn >> 9;
    int dout = nn & 511;
    float v = pw[(((size_t)(kp * 512 + dout) * 512) + din) * 3 + tap];
    HL r = split2(v);
    wh[gid] = r.h;
    wl[gid] = r.l;
}

// z[b,j,d] = block mean of residual (fp64 acc) -> split halves zh/zl
__global__ __launch_bounds__(256) void k_zmean(const float* __restrict__ resid,
        _Float16* __restrict__ zh, _Float16* __restrict__ zl, int s, int lg) {
    int gid = blockIdx.x * 256 + threadIdx.x;       // 16*s*512 threads
    int d = gid & 511;
    int j = (gid >> 9) & (s - 1);
    int b = gid >> (9 + lg);
    int r = 512 >> lg;
    const float* p = resid + ((size_t)((b << 9) + (j << (9 - lg))) << 9) + d;
    double acc = 0.0;
#pragma unroll 4
    for (int m = 0; m < r; ++m) acc += (double)p[(size_t)m * ND];
    float v = (float)(acc * (1.0 / (double)r));
    HL hl = split2(v);
    zh[gid] = hl.h;
    zl[gid] = hl.l;
}

// ---------------- dist pass 1: hh-only GEMM, 128x128 block, 2x2 waves ----------------
__global__ __launch_bounds__(256, 4) void k_dist1(const _Float16* __restrict__ zh,
        const _Float16* __restrict__ eh, const float* __restrict__ esq,
        unsigned long long* __restrict__ minbuf, unsigned int* __restrict__ cnt,
        unsigned long long* __restrict__ cand, int M) {
    __shared__ _Float16 smem[2][2][4096] __attribute__((aligned(16)));  // 32 KB
    // epilogue aliases (live only after the main loop's trailing barrier):
    unsigned long long (*packs)[2] = reinterpret_cast<unsigned long long(*)[2]>(&smem[0][0][0]); // 2 KB
    float* Tlds = reinterpret_cast<float*>(reinterpret_cast<char*>(&smem[0][0][0]) + 2048);      // 512 B
    int tid = threadIdx.x;
    int lane = tid & 63, wave = tid >> 6;
    int wm = wave >> 1, wn = wave & 1;
    int quad = lane >> 4, l15 = lane & 15;
    int m0 = blockIdx.x * 128, n0 = blockIdx.y * 128;

    int slot = lane & 3;
    int r0 = wave * 32 + (lane >> 2);
    int r1 = r0 + 16;
    int sc0 = (slot ^ ((r0 >> 1) & 3)) << 3;    // swizzled source col (halves)
    int sc1 = (slot ^ ((r1 >> 1) & 3)) << 3;
    int a0 = m0 + r0; if (a0 >= M) a0 = M - 1;
    int a1 = m0 + r1; if (a1 >= M) a1 = M - 1;
    const _Float16* gA0 = zh + (size_t)a0 * 512 + sc0;
    const _Float16* gA1 = zh + (size_t)a1 * 512 + sc1;
    const _Float16* gB0 = eh + (size_t)(n0 + r0) * 512 + sc0;
    const _Float16* gB1 = eh + (size_t)(n0 + r1) * 512 + sc1;
    int ld0 = wave * 1024, ld1 = ld0 + 512;

    int cslot = (quad ^ ((l15 >> 1) & 3)) << 3;
    int rbA = (wm * 64 + l15) * 32 + cslot;
    int rbB = (wn * 64 + l15) * 32 + cslot;

#define STG(buf, kb) do { \
    gl2lds16(gA0 + (kb), &smem[buf][0][ld0]); \
    gl2lds16(gA1 + (kb), &smem[buf][0][ld1]); \
    gl2lds16(gB0 + (kb), &smem[buf][1][ld0]); \
    gl2lds16(gB1 + (kb), &smem[buf][1][ld1]); \
} while (0)

    floatx4 acc[4][4];
#pragma unroll
    for (int i = 0; i < 4; ++i)
#pragma unroll
        for (int j = 0; j < 4; ++j)
#pragma unroll
            for (int r = 0; r < 4; ++r) acc[i][j][r] = 0.f;

    STG(0, 0);
    __syncthreads();
    int cur = 0;
    for (int it = 0; it < 16; ++it) {
        if (it < 15) STG(cur ^ 1, (it + 1) * 32);
        const _Float16* sA = &smem[cur][0][0];
        const _Float16* sB = &smem[cur][1][0];
        half8v af[4], bf[4];
#pragma unroll
        for (int tm = 0; tm < 4; ++tm) af[tm] = *(const half8v*)&sA[rbA + tm * 512];
#pragma unroll
        for (int tn = 0; tn < 4; ++tn) bf[tn] = *(const half8v*)&sB[rbB + tn * 512];
#pragma unroll
        for (int tm = 0; tm < 4; ++tm)
#pragma unroll
            for (int tn = 0; tn < 4; ++tn)
                acc[tm][tn] = __builtin_amdgcn_mfma_f32_16x16x32_f16(af[tm], bf[tn], acc[tm][tn], 0, 0, 0);
        __syncthreads();
        cur ^= 1;
    }
#undef STG
    float es[4];
#pragma unroll
    for (int tn = 0; tn < 4; ++tn) es[tn] = esq[n0 + wn * 64 + tn * 16 + l15];
    // loop 1: per-m block-min
#pragma unroll
    for (int tm = 0; tm < 4; ++tm)
#pragma unroll
        for (int reg = 0; reg < 4; ++reg) {
            unsigned long long best = ~0ull;
#pragma unroll
            for (int tn = 0; tn < 4; ++tn) {
                float dd = fmaf(-2.f, acc[tm][tn][reg], es[tn]);
                int n = n0 + wn * 64 + tn * 16 + l15;
                unsigned long long p = pack_dist(dd, n);
                best = p < best ? p : best;
            }
#pragma unroll
            for (int off = 1; off < 16; off <<= 1) {
                unsigned long long q = __shfl_xor(best, off, 64);
                best = q < best ? q : best;
            }
            if (l15 == 0) packs[wm * 64 + tm * 16 + quad * 4 + reg][wn] = best;
        }
    __syncthreads();
    if (tid < 128) {
        float T = -1e30f;
        int m = m0 + tid;
        if (m < M) {
            unsigned long long b0 = packs[tid][0], b1 = packs[tid][1];
            unsigned long long bm = b0 < b1 ? b0 : b1;
            unsigned long long old = atomicMin(&minbuf[m], bm);
            unsigned long long g = old < bm ? old : bm;
            T = unpack_dist(g) + DELTA;
        }
        Tlds[tid] = T;
    }
    __syncthreads();
    // loop 2: append qualifying candidates
#pragma unroll
    for (int tm = 0; tm < 4; ++tm)
#pragma unroll
        for (int reg = 0; reg < 4; ++reg) {
            int row = wm * 64 + tm * 16 + quad * 4 + reg;
            int m = m0 + row;
            float T = Tlds[row];
            if (m < M) {
#pragma unroll
                for (int tn = 0; tn < 4; ++tn) {
                    float dd = fmaf(-2.f, acc[tm][tn][reg], es[tn]);
                    if (dd <= T) {
                        int n = n0 + wn * 64 + tn * 16 + l15;
                        unsigned slotc = atomicAdd(&cnt[m], 1u);
                        if (slotc < CAP) cand[(size_t)m * CAP + slotc] = pack_dist(dd, n);
                    }
                }
            }
        }
}

// ---------------- dist pass 2: fp64-exact refine over appended candidates ----------------
__global__ __launch_bounds__(256) void k_refine(const _Float16* __restrict__ zh,
        const _Float16* __restrict__ zl, const float* __restrict__ embed,
        const unsigned long long* __restrict__ cand, const unsigned int* __restrict__ cnt,
        unsigned long long* __restrict__ minbuf, int M) {
    int lane = threadIdx.x & 63, wave = threadIdx.x >> 6;
    int m = blockIdx.x * 4 + wave;
    if (m >= M) return;
    float zr[8];
    const _Float16* ph = zh + (size_t)m * 512 + lane * 8;
    const _Float16* pl = zl + (size_t)m * 512 + lane * 8;
#pragma unroll
    for (int i = 0; i < 8; ++i)
        zr[i] = (float)ph[i] + (float)pl[i] * (1.0f / 4096.0f);
    unsigned c = cnt[m];
    float gd = unpack_dist(minbuf[m]) + DELTA;
    double bestD = 1e300;
    int bestI = 0x7fffffff;
    if (c <= CAP) {
        for (unsigned j = 0; j < c; ++j) {
            unsigned long long p = cand[(size_t)m * CAP + j];
            float d = unpack_dist(p);
            if (d <= gd) {
                int idx = (int)(unsigned)p;
                const float* e = embed + (size_t)idx * 512 + lane * 8;
                double s = 0.0;
#pragma unroll
                for (int i = 0; i < 8; ++i) {
                    double df = (double)zr[i] - (double)e[i];
                    s += df * df;
                }
#pragma unroll
                for (int off = 32; off > 0; off >>= 1) s += __shfl_down(s, off, 64);
                if (lane == 0) {
                    if (s < bestD || (s == bestD && idx < bestI)) { bestD = s; bestI = idx; }
                }
            }
        }
    } else {
        // overflow fallback (never expected): exact scan of all codes
        for (int idx = 0; idx < NCB; ++idx) {
            const float* e = embed + (size_t)idx * 512 + lane * 8;
            double s = 0.0;
#pragma unroll
            for (int i = 0; i < 8; ++i) {
                double df = (double)zr[i] - (double)e[i];
                s += df * df;
            }
#pragma unroll
            for (int off = 32; off > 0; off >>= 1) s += __shfl_down(s, off, 64);
            if (lane == 0) {
                if (s < bestD) { bestD = s; bestI = idx; }
            }
        }
    }
    if (lane == 0) minbuf[m] = (unsigned long long)(unsigned)bestI;
}

// ---------------- phi: u[m][tap*512+dout] = (W_tap q_m)[dout], m = b*s+j ----------------
__global__ __launch_bounds__(256, 2) void k_phi(const _Float16* __restrict__ eh,
        const _Float16* __restrict__ el, const _Float16* __restrict__ wh,
        const _Float16* __restrict__ wl, const unsigned long long* __restrict__ minbuf,
        float* __restrict__ u, int M) {
    __shared__ _Float16 smem[2][4][4096] __attribute__((aligned(16)));  // 64KB exactly
    int* idxs = reinterpret_cast<int*>(&smem[0][0][0]);
    int tid = threadIdx.x;
    int lane = tid & 63, wave = tid >> 6;
    int wm = wave >> 1, wn = wave & 1;
    int quad = lane >> 4, l15 = lane & 15;
    int m0 = blockIdx.x * 128, n0 = blockIdx.y * 128;
    if (tid < 128) {
        int m = m0 + tid; if (m >= M) m = M - 1;
        idxs[tid] = (int)(unsigned)minbuf[m];
    }
    __syncthreads();

    int slot = lane & 3;
    int r0 = wave * 32 + (lane >> 2);
    int r1 = r0 + 16;
    int sc0 = (slot ^ ((r0 >> 1) & 3)) << 3;
    int sc1 = (slot ^ ((r1 >> 1) & 3)) << 3;
    int code0 = idxs[r0];
    int code1 = idxs[r1];
    __syncthreads();   // all waves done reading idxs before DMA overwrites smem
    const _Float16* gA0h = eh + (size_t)code0 * 512 + sc0;
    const _Float16* gA1h = eh + (size_t)code1 * 512 + sc1;
    const _Float16* gA0l = el + (size_t)code0 * 512 + sc0;
    const _Float16* gA1l = el + (size_t)code1 * 512 + sc1;
    const _Float16* gB0h = wh + (size_t)(n0 + r0) * 512 + sc0;
    const _Float16* gB1h = wh + (size_t)(n0 + r1) * 512 + sc1;
    const _Float16* gB0l = wl + (size_t)(n0 + r0) * 512 + sc0;
    const _Float16* gB1l = wl + (size_t)(n0 + r1) * 512 + sc1;
    int ld0 = wave * 1024;
    int ld1 = ld0 + 512;

    int cslot = (quad ^ ((l15 >> 1) & 3)) << 3;
    int rbA = (wm * 64 + l15) * 32 + cslot;
    int rbB = (wn * 64 + l15) * 32 + cslot;

#define STAGE_P(buf, kb) do { \
    gl2lds16(gA0h + (kb), &smem[buf][0][ld0]); \
    gl2lds16(gA1h + (kb), &smem[buf][0][ld1]); \
    gl2lds16(gA0l + (kb), &smem[buf][1][ld0]); \
    gl2lds16(gA1l + (kb), &smem[buf][1][ld1]); \
    gl2lds16(gB0h + (kb), &smem[buf][2][ld0]); \
    gl2lds16(gB1h + (kb), &smem[buf][2][ld1]); \
    gl2lds16(gB0l + (kb), &smem[buf][3][ld0]); \
    gl2lds16(gB1l + (kb), &smem[buf][3][ld1]); \
} while (0)

    floatx4 acch[4][4], accx[4][4];
#pragma unroll
    for (int i = 0; i < 4; ++i)
#pragma unroll
        for (int j = 0; j < 4; ++j)
#pragma unroll
            for (int r = 0; r < 4; ++r) { acch[i][j][r] = 0.f; accx[i][j][r] = 0.f; }

    STAGE_P(0, 0);
    __syncthreads();
    int cur = 0;
    for (int it = 0; it < 16; ++it) {
        if (it < 15) STAGE_P(cur ^ 1, (it + 1) * 32);
        const _Float16* sAh = &smem[cur][0][0];
        const _Float16* sAl = &smem[cur][1][0];
        const _Float16* sBh = &smem[cur][2][0];
        const _Float16* sBl = &smem[cur][3][0];
        half8v afh[4], afl[4], bfh[4], bfl[4];
#pragma unroll
        for (int tm = 0; tm < 4; ++tm) {
            afh[tm] = *(const half8v*)&sAh[rbA + tm * 512];
            afl[tm] = *(const half8v*)&sAl[rbA + tm * 512];
        }
#pragma unroll
        for (int tn = 0; tn < 4; ++tn) {
            bfh[tn] = *(const half8v*)&sBh[rbB + tn * 512];
            bfl[tn] = *(const half8v*)&sBl[rbB + tn * 512];
        }
#pragma unroll
        for (int tm = 0; tm < 4; ++tm)
#pragma unroll
            for (int tn = 0; tn < 4; ++tn) {
                acch[tm][tn] = __builtin_amdgcn_mfma_f32_16x16x32_f16(afh[tm], bfh[tn], acch[tm][tn], 0, 0, 0);
                accx[tm][tn] = __builtin_amdgcn_mfma_f32_16x16x32_f16(afh[tm], bfl[tn], accx[tm][tn], 0, 0, 0);
                accx[tm][tn] = __builtin_amdgcn_mfma_f32_16x16x32_f16(afl[tm], bfh[tn], accx[tm][tn], 0, 0, 0);
            }
        __syncthreads();
        cur ^= 1;
    }
#undef STAGE_P
#pragma unroll
    for (int tm = 0; tm < 4; ++tm)
#pragma unroll
        for (int reg = 0; reg < 4; ++reg) {
            int m = m0 + wm * 64 + tm * 16 + quad * 4 + reg;
            if (m < M) {
#pragma unroll
                for (int tn = 0; tn < 4; ++tn) {
                    int n = n0 + wn * 64 + tn * 16 + l15;
                    u[(size_t)m * 1536 + n] = acch[tm][tn][reg] + accx[tm][tn][reg] * (1.0f / 4096.0f);
                }
            }
        }
}

// combine (s<=128): resid -= 0.5*h + 0.5*(conv+bias); h = lerp(embed[idx]),
// conv[t] = sum_tap lerp of u[.][tap] at t' = t+tap-1
__global__ __launch_bounds__(256) void k_combine(const float* __restrict__ u,
        const float* __restrict__ embed, const unsigned long long* __restrict__ minbuf,
        const float* __restrict__ bias, float* __restrict__ resid, int s, float scale) {
    int tid = threadIdx.x;
    int m = blockIdx.x * 2 + (tid >> 7);
    int d4 = (tid & 127) << 2;
    int b = m >> 9, t = m & 511;
    int bs = b * s;
    float4 bi = *(const float4*)(bias + d4);
    float uu = ((float)t + 0.5f) * scale - 0.5f;
    float fl = floorf(uu);
    float w = uu - fl;
    int i0 = (int)fl, i1 = i0 + 1;
    i0 = min(max(i0, 0), s - 1);
    i1 = min(max(i1, 0), s - 1);
    int c0 = (int)(unsigned)minbuf[bs + i0];
    int c1 = (int)(unsigned)minbuf[bs + i1];
    float4 e0 = *(const float4*)(embed + (size_t)c0 * 512 + d4);
    float4 e1 = *(const float4*)(embed + (size_t)c1 * 512 + d4);
    float om = 1.0f - w;
    float4 h4;
    h4.x = om * e0.x + w * e1.x; h4.y = om * e0.y + w * e1.y;
    h4.z = om * e0.z + w * e1.z; h4.w = om * e0.w + w * e1.w;
    float4 conv = make_float4(0.f, 0.f, 0.f, 0.f);
#pragma unroll
    for (int tap = 0; tap < 3; ++tap) {
        int tt = t + tap - 1;
        if (tt >= 0 && tt < 512) {
            float uu2 = ((float)tt + 0.5f) * scale - 0.5f;
            float fl2 = floorf(uu2);
            float w2 = uu2 - fl2;
            int j0 = (int)fl2, j1 = j0 + 1;
            j0 = min(max(j0, 0), s - 1);
            j1 = min(max(j1, 0), s - 1);
            float4 a4 = *(const float4*)(u + (size_t)(bs + j0) * 1536 + tap * 512 + d4);
            float4 b4 = *(const float4*)(u + (size_t)(bs + j1) * 1536 + tap * 512 + d4);
            float ow = 1.0f - w2;
            conv.x += ow * a4.x + w2 * b4.x;
            conv.y += ow * a4.y + w2 * b4.y;
            conv.z += ow * a4.z + w2 * b4.z;
            conv.w += ow * a4.w + w2 * b4.w;
        }
    }
    size_t off = (size_t)m * 512 + d4;
    float4 rv = *(float4*)(resid + off);
    rv.x -= 0.5f * h4.x + 0.5f * (conv.x + bi.x);
    rv.y -= 0.5f * h4.y + 0.5f * (conv.y + bi.y);
    rv.z -= 0.5f * h4.z + 0.5f * (conv.z + bi.z);
    rv.w -= 0.5f * h4.w + 0.5f * (conv.w + bi.w);
    *(float4*)(resid + off) = rv;
}

// direct conv (s in {256,512}): GEMM [8192 x 1536(tap,din)] x [1536 x 512(dout)]
// epilogue: r2 = resid - (0.5*h + 0.5*(conv+bias)); last ? out = x - r2 : resid = r2
__global__ __launch_bounds__(256, 2) void k_conv(const _Float16* __restrict__ eh,
        const _Float16* __restrict__ el, const float* __restrict__ embed,
        const _Float16* __restrict__ wh, const _Float16* __restrict__ wl,
        const float* __restrict__ bias, const unsigned long long* __restrict__ minbuf,
        float* __restrict__ resid, int s, float scale,
        const float* __restrict__ x, float* __restrict__ out, int last) {
    __shared__ _Float16 Ah[128][40], Al[128][40], Bh[128][40], Bl[128][40];
    __shared__ int c0s[132], c1s[132];
    __shared__ float wws[132];
    int tid = threadIdx.x;
    int lane = tid & 63, wave = tid >> 6;
    int wm = wave >> 1, wn = wave & 1;
    int quad = lane >> 4, l15 = lane & 15;
    int m0 = blockIdx.x * 128, n0 = blockIdx.y * 128;
    int b = m0 >> 9, t0 = m0 & 511, bs = b * s;
    int noint = (s == 512);
    if (tid < 130) {
        int tt = t0 + tid - 1;
        if (tt >= 0 && tt < 512) {
            float uu = ((float)tt + 0.5f) * scale - 0.5f;
            float fl = floorf(uu);
            float w = uu - fl;
            int i0 = (int)fl, i1 = i0 + 1;
            i0 = min(max(i0, 0), s - 1);
            i1 = min(max(i1, 0), s - 1);
            c0s[tid] = (int)(unsigned)minbuf[bs + i0];
            c1s[tid] = (int)(unsigned)minbuf[bs + i1];
            wws[tid] = w;
        } else { c0s[tid] = -1; c1s[tid] = -1; wws[tid] = 0.f; }
    }
    floatx4 acch[4][4], accx[4][4];
#pragma unroll
    for (int i = 0; i < 4; ++i)
#pragma unroll
        for (int j = 0; j < 4; ++j)
#pragma unroll
            for (int r = 0; r < 4; ++r) { acch[i][j][r] = 0.f; accx[i][j][r] = 0.f; }
    __syncthreads();
    for (int kb = 0; kb < 1536; kb += 32) {
        int tap = kb >> 9, din0 = kb & 511;
#pragma unroll
        for (int r = 0; r < 2; ++r) {
            int c = tid + r * 256;
            int row = c >> 2, c8 = c & 3;
            int j = row + tap;
            int cc0 = c0s[j], cc1 = c1s[j];
            half8v hh8, ll8;
            if (cc0 < 0) {
                hh8 = (half8v)(_Float16)0.f;
                ll8 = (half8v)(_Float16)0.f;
                *(half8v*)&Ah[row][c8 * 8] = hh8;
                *(half8v*)&Al[row][c8 * 8] = ll8;
            } else if (noint) {
                *(int4*)&Ah[row][c8 * 8] = *(const int4*)(eh + (size_t)cc0 * 512 + din0 + c8 * 8);
                *(int4*)&Al[row][c8 * 8] = *(const int4*)(el + (size_t)cc0 * 512 + din0 + c8 * 8);
            } else {
                float w = wws[j], ow = 1.0f - w;
                const float* p0 = embed + (size_t)cc0 * 512 + din0 + c8 * 8;
                const float* p1 = embed + (size_t)cc1 * 512 + din0 + c8 * 8;
                float4 a0 = *(const float4*)p0, a1 = *(const float4*)(p0 + 4);
                float4 b0 = *(const float4*)p1, b1 = *(const float4*)(p1 + 4);
                float vals[8];
                vals[0] = ow * a0.x + w * b0.x; vals[1] = ow * a0.y + w * b0.y;
                vals[2] = ow * a0.z + w * b0.z; vals[3] = ow * a0.w + w * b0.w;
                vals[4] = ow * a1.x + w * b1.x; vals[5] = ow * a1.y + w * b1.y;
                vals[6] = ow * a1.z + w * b1.z; vals[7] = ow * a1.w + w * b1.w;
#pragma unroll
                for (int q = 0; q < 8; ++q) {
                    HL hl = split2(vals[q]);
                    hh8[q] = hl.h; ll8[q] = hl.l;
                }
                *(half8v*)&Ah[row][c8 * 8] = hh8;
                *(half8v*)&Al[row][c8 * 8] = ll8;
            }
            int brow = tap * 512 + n0 + row;     // Wt2 row = tap*512 + dout
            *(int4*)&Bh[row][c8 * 8] = *(const int4*)(wh + (size_t)brow * 512 + din0 + c8 * 8);
            *(int4*)&Bl[row][c8 * 8] = *(const int4*)(wl + (size_t)brow * 512 + din0 + c8 * 8);
        }
        __syncthreads();
        half8v afh[4], afl[4], bfh[4], bfl[4];
#pragma unroll
        for (int tm = 0; tm < 4; ++tm) {
            afh[tm] = *(const half8v*)&Ah[wm * 64 + tm * 16 + l15][quad * 8];
            afl[tm] = *(const half8v*)&Al[wm * 64 + tm * 16 + l15][quad * 8];
        }
#pragma unroll
        for (int tn = 0; tn < 4; ++tn) {
            bfh[tn] = *(const half8v*)&Bh[wn * 64 + tn * 16 + l15][quad * 8];
            bfl[tn] = *(const half8v*)&Bl[wn * 64 + tn * 16 + l15][quad * 8];
        }
#pragma unroll
        for (int tm = 0; tm < 4; ++tm)
#pragma unroll
            for (int tn = 0; tn < 4; ++tn) {
                acch[tm][tn] = __builtin_amdgcn_mfma_f32_16x16x32_f16(afh[tm], bfh[tn], acch[tm][tn], 0, 0, 0);
                accx[tm][tn] = __builtin_amdgcn_mfma_f32_16x16x32_f16(afh[tm], bfl[tn], accx[tm][tn], 0, 0, 0);
                accx[tm][tn] = __builtin_amdgcn_mfma_f32_16x16x32_f16(afl[tm], bfh[tn], accx[tm][tn], 0, 0, 0);
            }
        __syncthreads();
    }
#pragma unroll
    for (int tm = 0; tm < 4; ++tm)
#pragma unroll
        for (int reg = 0; reg < 4; ++reg) {
            int row = wm * 64 + tm * 16 + quad * 4 + reg;
            int m = m0 + row;
            int jj = row + 1;                  // tap=1 -> t'=t
            int cc0 = c0s[jj], cc1 = c1s[jj];
            float w = wws[jj], ow = 1.0f - w;
#pragma unroll
            for (int tn = 0; tn < 4; ++tn) {
                int n = n0 + wn * 64 + tn * 16 + l15;
                float h = ow * embed[(size_t)cc0 * 512 + n] + w * embed[(size_t)cc1 * 512 + n];
                float val = acch[tm][tn][reg] + accx[tm][tn][reg] * (1.0f / 4096.0f);
                size_t off = (size_t)m * 512 + n;
                float r2 = resid[off] - (0.5f * h + 0.5f * (val + bias[n]));
                if (last) out[off] = x[off] - r2;
                else resid[off] = r2;
            }
        }
}

extern "C" void kernel_launch(void* const* d_in, const int* in_sizes, int n_in,
                              void* d_out, int out_size, void* d_ws, size_t ws_size,
                              hipStream_t stream) {
    const float* x     = (const float*)d_in[0];
    const float* embed = (const float*)d_in[1];
    const float* pw    = (const float*)d_in[2];
    const float* pb    = (const float*)d_in[3];
    float* out = (float*)d_out;

    // ws layout (floats), ~55.7 MB total:
    // resid 16MB | U 16MB (zh/zl halves; u<=12.6MB aliases after dist) |
    // ehi/elo 8MB | Wt2 hi/lo 12MB | esq 16KB | minbuf 64KB | cnt 32KB | cand 1MB
    float* resid = (float*)d_ws;
    float* Ubase = resid + 4194304;
    _Float16* zh = (_Float16*)Ubase;
    _Float16* zl = zh + 4194304;
    float* u = Ubase;
    _Float16* ehi = (_Float16*)(Ubase + 4194304);
    _Float16* elo = ehi + 2097152;
    _Float16* whi = elo + 2097152;
    _Float16* wlo = whi + 3145728;
    float* esq = (float*)(wlo + 3145728);
    unsigned long long* minbuf = (unsigned long long*)(esq + 4096);
    unsigned int* cntb = (unsigned int*)(minbuf + 8192);
    unsigned long long* cand = (unsigned long long*)(cntb + 8192);

    k_esq<<<1024, 256, 0, stream>>>(embed, esq);
    k_split_embed<<<2048, 256, 0, stream>>>(embed, ehi, elo);
    k_split_w<<<12288, 256, 0, stream>>>(pw, whi, wlo);
    k_copy<<<4096, 256, 0, stream>>>(x, resid);

    const int SCv[10] = {1, 2, 4, 8, 16, 32, 64, 128, 256, 512};
    // PHI_IDX with float64-ulp tie-breaks at si=2 and si=7 (verified round 2)
    const int PIv[10] = {0, 0, 1, 1, 1, 2, 2, 3, 3, 3};
    for (int si = 0; si < 10; ++si) {
        int s = SCv[si];
        int M = 16 * s;
        int kp = PIv[si];
        int lg = __builtin_ctz((unsigned)s);
        float scale = (float)s / 512.0f;
        k_zmean<<<(M * 512) / 256, 256, 0, stream>>>(resid, zh, zl, s, lg);
        (void)hipMemsetAsync(minbuf, 0xFF, (size_t)M * 8, stream);
        (void)hipMemsetAsync(cntb, 0, (size_t)M * 4, stream);
        k_dist1<<<dim3((M + 127) / 128, 32), 256, 0, stream>>>(zh, ehi, esq, minbuf, cntb, cand, M);
        k_refine<<<(M + 3) / 4, 256, 0, stream>>>(zh, zl, embed, cand, cntb, minbuf, M);
        if (s <= 128) {
            k_phi<<<dim3((M + 127) / 128, 12), 256, 0, stream>>>(ehi, elo,
                    whi + (size_t)kp * 1536 * 512, wlo + (size_t)kp * 1536 * 512, minbuf, u, M);
            k_combine<<<4096, 256, 0, stream>>>(u, embed, minbuf, pb + kp * 512, resid, s, scale);
        } else {
            k_conv<<<dim3(64, 4), 256, 0, stream>>>(ehi, elo, embed,
                    whi + (size_t)kp * 1536 * 512, wlo + (size_t)kp * 1536 * 512,
                    pb + kp * 512, minbuf, resid, s, scale, x, out, si == 9 ? 1 : 0);
        }
    }
}

// Round 4
// 964.807 us; speedup vs baseline: 1.1177x; 1.1177x over previous
//
#include <hip/hip_runtime.h>

// Multiscale Residual VQ (VAR-style), MI355X gfx950.
// Round 9:
//   - dist1 candidate fix: CAP 32, loop-2 re-reads minbuf[m] (fresh threshold)
//     before appending -> appends ~1-3/m, no CAP overflow, k_refine stays tiny.
//     (Round 8's overflow: every n-block self-appended its local min vs stale
//     global -> cnt>16 -> fp64 full-scan fallback, race-dependent +100us.)
//   - k_conv retile: BM=64 x BN=128, grid (128,4)=512 blocks = 2 blocks/CU
//     (was 256 = 1/CU -> Occupancy 11%, MfmaUtil 12%). Unpadded [.][32] LDS
//     with slot^((row>>1)&3) XOR swizzle on ds_write + read (conflict-free,
//     same involution family as dist). MFMA order per (m,n) unchanged ->
//     bit-identical conv output.
// k_dist1 GEMM core / k_phi / k_combine / pre-pass unchanged from round 8.

#define ND 512
#define NCB 4096
#define CAP 32
#define DELTA 0.5f

typedef _Float16 half8v __attribute__((ext_vector_type(8)));
typedef float floatx4 __attribute__((ext_vector_type(4)));

struct HL { _Float16 h, l; };

__device__ __forceinline__ HL split2(float v) {
    HL r;
    r.h = (_Float16)v;
    r.l = (_Float16)((v - (float)r.h) * 4096.0f);
    return r;
}

__device__ __forceinline__ unsigned long long pack_dist(float d, int n) {
    unsigned u = __float_as_uint(d);
    u = (u & 0x80000000u) ? ~u : (u | 0x80000000u);   // monotone total order
    return ((unsigned long long)u << 32) | (unsigned)n; // tie -> lowest idx
}

__device__ __forceinline__ float unpack_dist(unsigned long long p) {
    unsigned u = (unsigned)(p >> 32);
    u = (u & 0x80000000u) ? (u & 0x7fffffffu) : ~u;
    return __uint_as_float(u);
}

// async global->LDS, 16B per lane; LDS dest = wave-uniform base + lane*16
__device__ __forceinline__ void gl2lds16(const _Float16* g, _Float16* l) {
    __builtin_amdgcn_global_load_lds(
        (const __attribute__((address_space(1))) unsigned int*)g,
        (__attribute__((address_space(3))) unsigned int*)l, 16, 0, 0);
}

// e_sq[c] = sum_d embed[c,d]^2, fp64 accumulate
__global__ __launch_bounds__(256) void k_esq(const float* __restrict__ embed,
                                             float* __restrict__ esq) {
    int c = blockIdx.x * 4 + (threadIdx.x >> 6);
    int lane = threadIdx.x & 63;
    const float* row = embed + (size_t)c * ND;
    double acc = 0.0;
#pragma unroll
    for (int i = 0; i < ND / 64; ++i) {
        float v = row[lane + i * 64];
        acc += (double)v * (double)v;
    }
#pragma unroll
    for (int off = 32; off > 0; off >>= 1) acc += __shfl_down(acc, off, 64);
    if (lane == 0) esq[c] = (float)acc;
}

__global__ __launch_bounds__(256) void k_copy(const float* __restrict__ src,
                                              float* __restrict__ dst) {
    int gid = blockIdx.x * 256 + threadIdx.x;
    ((float4*)dst)[gid] = ((const float4*)src)[gid];
}

// embed -> ehi/elo (4096x512 halves)
__global__ __launch_bounds__(256) void k_split_embed(const float* __restrict__ embed,
        _Float16* __restrict__ eh, _Float16* __restrict__ el) {
    int gid = blockIdx.x * 256 + threadIdx.x;       // 524288 float4s
    float4 v = ((const float4*)embed)[gid];
    HL a = split2(v.x), b = split2(v.y), c = split2(v.z), d = split2(v.w);
    _Float16* ph = eh + (size_t)gid * 4;
    _Float16* pl = el + (size_t)gid * 4;
    ph[0] = a.h; ph[1] = b.h; ph[2] = c.h; ph[3] = d.h;
    pl[0] = a.l; pl[1] = b.l; pl[2] = c.l; pl[3] = d.l;
}

// Wt2[kp][tap*512+dout][din] hi/lo from pw[kp][dout][din][tap]; output-indexed
__global__ __launch_bounds__(256) void k_split_w(const float* __restrict__ pw,
        _Float16* __restrict__ wh, _Float16* __restrict__ wl) {
    int gid = blockIdx.x * 256 + threadIdx.x;       // 4*1536*512 = 3,145,728
    int din = gid & 511;
    int nn = (gid >> 9) % 1536;
    int kp = gid / (512 * 1536);
    int tap = nn >> 9;
    int dout = nn & 511;
    float v = pw[(((size_t)(kp * 512 + dout) * 512) + din) * 3 + tap];
    HL r = split2(v);
    wh[gid] = r.h;
    wl[gid] = r.l;
}

// z[b,j,d] = block mean of residual (fp64 acc) -> split halves zh/zl
__global__ __launch_bounds__(256) void k_zmean(const float* __restrict__ resid,
        _Float16* __restrict__ zh, _Float16* __restrict__ zl, int s, int lg) {
    int gid = blockIdx.x * 256 + threadIdx.x;       // 16*s*512 threads
    int d = gid & 511;
    int j = (gid >> 9) & (s - 1);
    int b = gid >> (9 + lg);
    int r = 512 >> lg;
    const float* p = resid + ((size_t)((b << 9) + (j << (9 - lg))) << 9) + d;
    double acc = 0.0;
#pragma unroll 4
    for (int m = 0; m < r; ++m) acc += (double)p[(size_t)m * ND];
    float v = (float)(acc * (1.0 / (double)r));
    HL hl = split2(v);
    zh[gid] = hl.h;
    zl[gid] = hl.l;
}

// ---------------- dist pass 1: hh-only GEMM, 128x128 block, 2x2 waves ----------------
__global__ __launch_bounds__(256, 4) void k_dist1(const _Float16* __restrict__ zh,
        const _Float16* __restrict__ eh, const float* __restrict__ esq,
        unsigned long long* __restrict__ minbuf, unsigned int* __restrict__ cnt,
        unsigned long long* __restrict__ cand, int M) {
    __shared__ _Float16 smem[2][2][4096] __attribute__((aligned(16)));  // 32 KB
    // epilogue aliases (live only after the main loop's trailing barrier):
    unsigned long long (*packs)[2] = reinterpret_cast<unsigned long long(*)[2]>(&smem[0][0][0]); // 2 KB
    float* Tlds = reinterpret_cast<float*>(reinterpret_cast<char*>(&smem[0][0][0]) + 2048);      // 512 B
    int tid = threadIdx.x;
    int lane = tid & 63, wave = tid >> 6;
    int wm = wave >> 1, wn = wave & 1;
    int quad = lane >> 4, l15 = lane & 15;
    int m0 = blockIdx.x * 128, n0 = blockIdx.y * 128;

    int slot = lane & 3;
    int r0 = wave * 32 + (lane >> 2);
    int r1 = r0 + 16;
    int sc0 = (slot ^ ((r0 >> 1) & 3)) << 3;    // swizzled source col (halves)
    int sc1 = (slot ^ ((r1 >> 1) & 3)) << 3;
    int a0 = m0 + r0; if (a0 >= M) a0 = M - 1;
    int a1 = m0 + r1; if (a1 >= M) a1 = M - 1;
    const _Float16* gA0 = zh + (size_t)a0 * 512 + sc0;
    const _Float16* gA1 = zh + (size_t)a1 * 512 + sc1;
    const _Float16* gB0 = eh + (size_t)(n0 + r0) * 512 + sc0;
    const _Float16* gB1 = eh + (size_t)(n0 + r1) * 512 + sc1;
    int ld0 = wave * 1024, ld1 = ld0 + 512;

    int cslot = (quad ^ ((l15 >> 1) & 3)) << 3;
    int rbA = (wm * 64 + l15) * 32 + cslot;
    int rbB = (wn * 64 + l15) * 32 + cslot;

#define STG(buf, kb) do { \
    gl2lds16(gA0 + (kb), &smem[buf][0][ld0]); \
    gl2lds16(gA1 + (kb), &smem[buf][0][ld1]); \
    gl2lds16(gB0 + (kb), &smem[buf][1][ld0]); \
    gl2lds16(gB1 + (kb), &smem[buf][1][ld1]); \
} while (0)

    floatx4 acc[4][4];
#pragma unroll
    for (int i = 0; i < 4; ++i)
#pragma unroll
        for (int j = 0; j < 4; ++j)
#pragma unroll
            for (int r = 0; r < 4; ++r) acc[i][j][r] = 0.f;

    STG(0, 0);
    __syncthreads();
    int cur = 0;
    for (int it = 0; it < 16; ++it) {
        if (it < 15) STG(cur ^ 1, (it + 1) * 32);
        const _Float16* sA = &smem[cur][0][0];
        const _Float16* sB = &smem[cur][1][0];
        half8v af[4], bf[4];
#pragma unroll
        for (int tm = 0; tm < 4; ++tm) af[tm] = *(const half8v*)&sA[rbA + tm * 512];
#pragma unroll
        for (int tn = 0; tn < 4; ++tn) bf[tn] = *(const half8v*)&sB[rbB + tn * 512];
#pragma unroll
        for (int tm = 0; tm < 4; ++tm)
#pragma unroll
            for (int tn = 0; tn < 4; ++tn)
                acc[tm][tn] = __builtin_amdgcn_mfma_f32_16x16x32_f16(af[tm], bf[tn], acc[tm][tn], 0, 0, 0);
        __syncthreads();
        cur ^= 1;
    }
#undef STG
    float es[4];
#pragma unroll
    for (int tn = 0; tn < 4; ++tn) es[tn] = esq[n0 + wn * 64 + tn * 16 + l15];
    // loop 1: per-m block-min
#pragma unroll
    for (int tm = 0; tm < 4; ++tm)
#pragma unroll
        for (int reg = 0; reg < 4; ++reg) {
            unsigned long long best = ~0ull;
#pragma unroll
            for (int tn = 0; tn < 4; ++tn) {
                float dd = fmaf(-2.f, acc[tm][tn][reg], es[tn]);
                int n = n0 + wn * 64 + tn * 16 + l15;
                unsigned long long p = pack_dist(dd, n);
                best = p < best ? p : best;
            }
#pragma unroll
            for (int off = 1; off < 16; off <<= 1) {
                unsigned long long q = __shfl_xor(best, off, 64);
                best = q < best ? q : best;
            }
            if (l15 == 0) packs[wm * 64 + tm * 16 + quad * 4 + reg][wn] = best;
        }
    __syncthreads();
    if (tid < 128) {
        float T = -1e30f;
        int m = m0 + tid;
        if (m < M) {
            unsigned long long b0 = packs[tid][0], b1 = packs[tid][1];
            unsigned long long bm = b0 < b1 ? b0 : b1;
            unsigned long long old = atomicMin(&minbuf[m], bm);
            unsigned long long g = old < bm ? old : bm;
            T = unpack_dist(g) + DELTA;
        }
        Tlds[tid] = T;
    }
    __syncthreads();
    // loop 2: append qualifying candidates (re-read global min -> tight T)
#pragma unroll
    for (int tm = 0; tm < 4; ++tm)
#pragma unroll
        for (int reg = 0; reg < 4; ++reg) {
            int row = wm * 64 + tm * 16 + quad * 4 + reg;
            int m = m0 + row;
            float T = Tlds[row];
            if (m < M) {
#pragma unroll
                for (int tn = 0; tn < 4; ++tn) {
                    float dd = fmaf(-2.f, acc[tm][tn][reg], es[tn]);
                    if (dd <= T) {
                        // refresh threshold from global (monotone-decreasing ->
                        // any stale read is a SAFE (>= final) threshold)
                        float Tf = unpack_dist(minbuf[m]) + DELTA;
                        if (dd <= Tf) {
                            int n = n0 + wn * 64 + tn * 16 + l15;
                            unsigned slotc = atomicAdd(&cnt[m], 1u);
                            if (slotc < CAP) cand[(size_t)m * CAP + slotc] = pack_dist(dd, n);
                        }
                    }
                }
            }
        }
}

// ---------------- dist pass 2: fp64-exact refine over appended candidates ----------------
__global__ __launch_bounds__(256) void k_refine(const _Float16* __restrict__ zh,
        const _Float16* __restrict__ zl, const float* __restrict__ embed,
        const unsigned long long* __restrict__ cand, const unsigned int* __restrict__ cnt,
        unsigned long long* __restrict__ minbuf, int M) {
    int lane = threadIdx.x & 63, wave = threadIdx.x >> 6;
    int m = blockIdx.x * 4 + wave;
    if (m >= M) return;
    float zr[8];
    const _Float16* ph = zh + (size_t)m * 512 + lane * 8;
    const _Float16* pl = zl + (size_t)m * 512 + lane * 8;
#pragma unroll
    for (int i = 0; i < 8; ++i)
        zr[i] = (float)ph[i] + (float)pl[i] * (1.0f / 4096.0f);
    unsigned c = cnt[m];
    float gd = unpack_dist(minbuf[m]) + DELTA;
    double bestD = 1e300;
    int bestI = 0x7fffffff;
    if (c <= CAP) {
        for (unsigned j = 0; j < c; ++j) {
            unsigned long long p = cand[(size_t)m * CAP + j];
            float d = unpack_dist(p);
            if (d <= gd) {
                int idx = (int)(unsigned)p;
                const float* e = embed + (size_t)idx * 512 + lane * 8;
                double s = 0.0;
#pragma unroll
                for (int i = 0; i < 8; ++i) {
                    double df = (double)zr[i] - (double)e[i];
                    s += df * df;
                }
#pragma unroll
                for (int off = 32; off > 0; off >>= 1) s += __shfl_down(s, off, 64);
                if (lane == 0) {
                    if (s < bestD || (s == bestD && idx < bestI)) { bestD = s; bestI = idx; }
                }
            }
        }
    } else {
        // overflow fallback (never expected): exact scan of all codes
        for (int idx = 0; idx < NCB; ++idx) {
            const float* e = embed + (size_t)idx * 512 + lane * 8;
            double s = 0.0;
#pragma unroll
            for (int i = 0; i < 8; ++i) {
                double df = (double)zr[i] - (double)e[i];
                s += df * df;
            }
#pragma unroll
            for (int off = 32; off > 0; off >>= 1) s += __shfl_down(s, off, 64);
            if (lane == 0) {
                if (s < bestD) { bestD = s; bestI = idx; }
            }
        }
    }
    if (lane == 0) minbuf[m] = (unsigned long long)(unsigned)bestI;
}

// ---------------- phi: u[m][tap*512+dout] = (W_tap q_m)[dout], m = b*s+j ----------------
__global__ __launch_bounds__(256, 2) void k_phi(const _Float16* __restrict__ eh,
        const _Float16* __restrict__ el, const _Float16* __restrict__ wh,
        const _Float16* __restrict__ wl, const unsigned long long* __restrict__ minbuf,
        float* __restrict__ u, int M) {
    __shared__ _Float16 smem[2][4][4096] __attribute__((aligned(16)));  // 64KB exactly
    int* idxs = reinterpret_cast<int*>(&smem[0][0][0]);
    int tid = threadIdx.x;
    int lane = tid & 63, wave = tid >> 6;
    int wm = wave >> 1, wn = wave & 1;
    int quad = lane >> 4, l15 = lane & 15;
    int m0 = blockIdx.x * 128, n0 = blockIdx.y * 128;
    if (tid < 128) {
        int m = m0 + tid; if (m >= M) m = M - 1;
        idxs[tid] = (int)(unsigned)minbuf[m];
    }
    __syncthreads();

    int slot = lane & 3;
    int r0 = wave * 32 + (lane >> 2);
    int r1 = r0 + 16;
    int sc0 = (slot ^ ((r0 >> 1) & 3)) << 3;
    int sc1 = (slot ^ ((r1 >> 1) & 3)) << 3;
    int code0 = idxs[r0];
    int code1 = idxs[r1];
    __syncthreads();   // all waves done reading idxs before DMA overwrites smem
    const _Float16* gA0h = eh + (size_t)code0 * 512 + sc0;
    const _Float16* gA1h = eh + (size_t)code1 * 512 + sc1;
    const _Float16* gA0l = el + (size_t)code0 * 512 + sc0;
    const _Float16* gA1l = el + (size_t)code1 * 512 + sc1;
    const _Float16* gB0h = wh + (size_t)(n0 + r0) * 512 + sc0;
    const _Float16* gB1h = wh + (size_t)(n0 + r1) * 512 + sc1;
    const _Float16* gB0l = wl + (size_t)(n0 + r0) * 512 + sc0;
    const _Float16* gB1l = wl + (size_t)(n0 + r1) * 512 + sc1;
    int ld0 = wave * 1024;
    int ld1 = ld0 + 512;

    int cslot = (quad ^ ((l15 >> 1) & 3)) << 3;
    int rbA = (wm * 64 + l15) * 32 + cslot;
    int rbB = (wn * 64 + l15) * 32 + cslot;

#define STAGE_P(buf, kb) do { \
    gl2lds16(gA0h + (kb), &smem[buf][0][ld0]); \
    gl2lds16(gA1h + (kb), &smem[buf][0][ld1]); \
    gl2lds16(gA0l + (kb), &smem[buf][1][ld0]); \
    gl2lds16(gA1l + (kb), &smem[buf][1][ld1]); \
    gl2lds16(gB0h + (kb), &smem[buf][2][ld0]); \
    gl2lds16(gB1h + (kb), &smem[buf][2][ld1]); \
    gl2lds16(gB0l + (kb), &smem[buf][3][ld0]); \
    gl2lds16(gB1l + (kb), &smem[buf][3][ld1]); \
} while (0)

    floatx4 acch[4][4], accx[4][4];
#pragma unroll
    for (int i = 0; i < 4; ++i)
#pragma unroll
        for (int j = 0; j < 4; ++j)
#pragma unroll
            for (int r = 0; r < 4; ++r) { acch[i][j][r] = 0.f; accx[i][j][r] = 0.f; }

    STAGE_P(0, 0);
    __syncthreads();
    int cur = 0;
    for (int it = 0; it < 16; ++it) {
        if (it < 15) STAGE_P(cur ^ 1, (it + 1) * 32);
        const _Float16* sAh = &smem[cur][0][0];
        const _Float16* sAl = &smem[cur][1][0];
        const _Float16* sBh = &smem[cur][2][0];
        const _Float16* sBl = &smem[cur][3][0];
        half8v afh[4], afl[4], bfh[4], bfl[4];
#pragma unroll
        for (int tm = 0; tm < 4; ++tm) {
            afh[tm] = *(const half8v*)&sAh[rbA + tm * 512];
            afl[tm] = *(const half8v*)&sAl[rbA + tm * 512];
        }
#pragma unroll
        for (int tn = 0; tn < 4; ++tn) {
            bfh[tn] = *(const half8v*)&sBh[rbB + tn * 512];
            bfl[tn] = *(const half8v*)&sBl[rbB + tn * 512];
        }
#pragma unroll
        for (int tm = 0; tm < 4; ++tm)
#pragma unroll
            for (int tn = 0; tn < 4; ++tn) {
                acch[tm][tn] = __builtin_amdgcn_mfma_f32_16x16x32_f16(afh[tm], bfh[tn], acch[tm][tn], 0, 0, 0);
                accx[tm][tn] = __builtin_amdgcn_mfma_f32_16x16x32_f16(afh[tm], bfl[tn], accx[tm][tn], 0, 0, 0);
                accx[tm][tn] = __builtin_amdgcn_mfma_f32_16x16x32_f16(afl[tm], bfh[tn], accx[tm][tn], 0, 0, 0);
            }
        __syncthreads();
        cur ^= 1;
    }
#undef STAGE_P
#pragma unroll
    for (int tm = 0; tm < 4; ++tm)
#pragma unroll
        for (int reg = 0; reg < 4; ++reg) {
            int m = m0 + wm * 64 + tm * 16 + quad * 4 + reg;
            if (m < M) {
#pragma unroll
                for (int tn = 0; tn < 4; ++tn) {
                    int n = n0 + wn * 64 + tn * 16 + l15;
                    u[(size_t)m * 1536 + n] = acch[tm][tn][reg] + accx[tm][tn][reg] * (1.0f / 4096.0f);
                }
            }
        }
}

// combine (s<=128): resid -= 0.5*h + 0.5*(conv+bias); h = lerp(embed[idx]),
// conv[t] = sum_tap lerp of u[.][tap] at t' = t+tap-1
__global__ __launch_bounds__(256) void k_combine(const float* __restrict__ u,
        const float* __restrict__ embed, const unsigned long long* __restrict__ minbuf,
        const float* __restrict__ bias, float* __restrict__ resid, int s, float scale) {
    int tid = threadIdx.x;
    int m = blockIdx.x * 2 + (tid >> 7);
    int d4 = (tid & 127) << 2;
    int b = m >> 9, t = m & 511;
    int bs = b * s;
    float4 bi = *(const float4*)(bias + d4);
    float uu = ((float)t + 0.5f) * scale - 0.5f;
    float fl = floorf(uu);
    float w = uu - fl;
    int i0 = (int)fl, i1 = i0 + 1;
    i0 = min(max(i0, 0), s - 1);
    i1 = min(max(i1, 0), s - 1);
    int c0 = (int)(unsigned)minbuf[bs + i0];
    int c1 = (int)(unsigned)minbuf[bs + i1];
    float4 e0 = *(const float4*)(embed + (size_t)c0 * 512 + d4);
    float4 e1 = *(const float4*)(embed + (size_t)c1 * 512 + d4);
    float om = 1.0f - w;
    float4 h4;
    h4.x = om * e0.x + w * e1.x; h4.y = om * e0.y + w * e1.y;
    h4.z = om * e0.z + w * e1.z; h4.w = om * e0.w + w * e1.w;
    float4 conv = make_float4(0.f, 0.f, 0.f, 0.f);
#pragma unroll
    for (int tap = 0; tap < 3; ++tap) {
        int tt = t + tap - 1;
        if (tt >= 0 && tt < 512) {
            float uu2 = ((float)tt + 0.5f) * scale - 0.5f;
            float fl2 = floorf(uu2);
            float w2 = uu2 - fl2;
            int j0 = (int)fl2, j1 = j0 + 1;
            j0 = min(max(j0, 0), s - 1);
            j1 = min(max(j1, 0), s - 1);
            float4 a4 = *(const float4*)(u + (size_t)(bs + j0) * 1536 + tap * 512 + d4);
            float4 b4 = *(const float4*)(u + (size_t)(bs + j1) * 1536 + tap * 512 + d4);
            float ow = 1.0f - w2;
            conv.x += ow * a4.x + w2 * b4.x;
            conv.y += ow * a4.y + w2 * b4.y;
            conv.z += ow * a4.z + w2 * b4.z;
            conv.w += ow * a4.w + w2 * b4.w;
        }
    }
    size_t off = (size_t)m * 512 + d4;
    float4 rv = *(float4*)(resid + off);
    rv.x -= 0.5f * h4.x + 0.5f * (conv.x + bi.x);
    rv.y -= 0.5f * h4.y + 0.5f * (conv.y + bi.y);
    rv.z -= 0.5f * h4.z + 0.5f * (conv.z + bi.z);
    rv.w -= 0.5f * h4.w + 0.5f * (conv.w + bi.w);
    *(float4*)(resid + off) = rv;
}

// direct conv (s in {256,512}): GEMM [8192 x 1536(tap,din)] x [1536 x 512(dout)]
// BM=64 x BN=128, 512 blocks (2/CU). Swizzled unpadded LDS (write+read XOR).
// epilogue: r2 = resid - (0.5*h + 0.5*(conv+bias)); last ? out = x - r2 : resid = r2
__global__ __launch_bounds__(256, 2) void k_conv(const _Float16* __restrict__ eh,
        const _Float16* __restrict__ el, const float* __restrict__ embed,
        const _Float16* __restrict__ wh, const _Float16* __restrict__ wl,
        const float* __restrict__ bias, const unsigned long long* __restrict__ minbuf,
        float* __restrict__ resid, int s, float scale,
        const float* __restrict__ x, float* __restrict__ out, int last) {
    __shared__ _Float16 Ah[64][32], Al[64][32], Bh[128][32], Bl[128][32];
    __shared__ int c0s[68], c1s[68];
    __shared__ float wws[68];
    int tid = threadIdx.x;
    int lane = tid & 63, wave = tid >> 6;
    int wm = wave >> 1, wn = wave & 1;
    int quad = lane >> 4, l15 = lane & 15;
    int m0 = blockIdx.x * 64, n0 = blockIdx.y * 128;
    int b = m0 >> 9, t0 = m0 & 511, bs = b * s;
    int noint = (s == 512);
    if (tid < 66) {
        int tt = t0 + tid - 1;
        if (tt >= 0 && tt < 512) {
            float uu = ((float)tt + 0.5f) * scale - 0.5f;
            float fl = floorf(uu);
            float w = uu - fl;
            int i0 = (int)fl, i1 = i0 + 1;
            i0 = min(max(i0, 0), s - 1);
            i1 = min(max(i1, 0), s - 1);
            c0s[tid] = (int)(unsigned)minbuf[bs + i0];
            c1s[tid] = (int)(unsigned)minbuf[bs + i1];
            wws[tid] = w;
        } else { c0s[tid] = -1; c1s[tid] = -1; wws[tid] = 0.f; }
    }
    floatx4 acch[2][4], accx[2][4];
#pragma unroll
    for (int i = 0; i < 2; ++i)
#pragma unroll
        for (int j = 0; j < 4; ++j)
#pragma unroll
            for (int r = 0; r < 4; ++r) { acch[i][j][r] = 0.f; accx[i][j][r] = 0.f; }
    // staging decomposition: A one (row,slot)/thread, B two
    int arow = tid >> 2, aslot = tid & 3;
    int asw = (aslot ^ ((arow >> 1) & 3)) << 3;     // swizzled LDS col (halves)
    __syncthreads();
    for (int kb = 0; kb < 1536; kb += 32) {
        int tap = kb >> 9, din0 = kb & 511;
        // ---- A tile: 64 rows x 32 halves, h/l
        {
            int j = arow + tap;
            int cc0 = c0s[j], cc1 = c1s[j];
            if (cc0 < 0) {
                *(half8v*)&Ah[arow][asw] = (half8v)(_Float16)0.f;
                *(half8v*)&Al[arow][asw] = (half8v)(_Float16)0.f;
            } else if (noint) {
                *(int4*)&Ah[arow][asw] = *(const int4*)(eh + (size_t)cc0 * 512 + din0 + aslot * 8);
                *(int4*)&Al[arow][asw] = *(const int4*)(el + (size_t)cc0 * 512 + din0 + aslot * 8);
            } else {
                float w = wws[j], ow = 1.0f - w;
                const float* p0 = embed + (size_t)cc0 * 512 + din0 + aslot * 8;
                const float* p1 = embed + (size_t)cc1 * 512 + din0 + aslot * 8;
                float4 a0 = *(const float4*)p0, a1 = *(const float4*)(p0 + 4);
                float4 b0 = *(const float4*)p1, b1 = *(const float4*)(p1 + 4);
                float vals[8];
                vals[0] = ow * a0.x + w * b0.x; vals[1] = ow * a0.y + w * b0.y;
                vals[2] = ow * a0.z + w * b0.z; vals[3] = ow * a0.w + w * b0.w;
                vals[4] = ow * a1.x + w * b1.x; vals[5] = ow * a1.y + w * b1.y;
                vals[6] = ow * a1.z + w * b1.z; vals[7] = ow * a1.w + w * b1.w;
                half8v hh8, ll8;
#pragma unroll
                for (int q = 0; q < 8; ++q) {
                    HL hl = split2(vals[q]);
                    hh8[q] = hl.h; ll8[q] = hl.l;
                }
                *(half8v*)&Ah[arow][asw] = hh8;
                *(half8v*)&Al[arow][asw] = ll8;
            }
        }
        // ---- B tile: 128 rows x 32 halves, h/l
#pragma unroll
        for (int r = 0; r < 2; ++r) {
            int c = tid + r * 256;
            int brw = c >> 2, bslot = c & 3;
            int bsw = (bslot ^ ((brw >> 1) & 3)) << 3;
            int brow = tap * 512 + n0 + brw;     // Wt2 row = tap*512 + dout
            *(int4*)&Bh[brw][bsw] = *(const int4*)(wh + (size_t)brow * 512 + din0 + bslot * 8);
            *(int4*)&Bl[brw][bsw] = *(const int4*)(wl + (size_t)brow * 512 + din0 + bslot * 8);
        }
        __syncthreads();
        half8v afh[2], afl[2], bfh[4], bfl[4];
#pragma unroll
        for (int tm = 0; tm < 2; ++tm) {
            int rA = wm * 32 + tm * 16 + l15;
            int cs = (quad ^ ((rA >> 1) & 3)) << 3;
            afh[tm] = *(const half8v*)&Ah[rA][cs];
            afl[tm] = *(const half8v*)&Al[rA][cs];
        }
#pragma unroll
        for (int tn = 0; tn < 4; ++tn) {
            int rB = wn * 64 + tn * 16 + l15;
            int cs = (quad ^ ((rB >> 1) & 3)) << 3;
            bfh[tn] = *(const half8v*)&Bh[rB][cs];
            bfl[tn] = *(const half8v*)&Bl[rB][cs];
        }
#pragma unroll
        for (int tm = 0; tm < 2; ++tm)
#pragma unroll
            for (int tn = 0; tn < 4; ++tn) {
                acch[tm][tn] = __builtin_amdgcn_mfma_f32_16x16x32_f16(afh[tm], bfh[tn], acch[tm][tn], 0, 0, 0);
                accx[tm][tn] = __builtin_amdgcn_mfma_f32_16x16x32_f16(afh[tm], bfl[tn], accx[tm][tn], 0, 0, 0);
                accx[tm][tn] = __builtin_amdgcn_mfma_f32_16x16x32_f16(afl[tm], bfh[tn], accx[tm][tn], 0, 0, 0);
            }
        __syncthreads();
    }
#pragma unroll
    for (int tm = 0; tm < 2; ++tm)
#pragma unroll
        for (int reg = 0; reg < 4; ++reg) {
            int row = wm * 32 + tm * 16 + quad * 4 + reg;
            int m = m0 + row;
            int jj = row + 1;                  // tap=1 -> t'=t
            int cc0 = c0s[jj], cc1 = c1s[jj];
            float w = wws[jj], ow = 1.0f - w;
#pragma unroll
            for (int tn = 0; tn < 4; ++tn) {
                int n = n0 + wn * 64 + tn * 16 + l15;
                float h = ow * embed[(size_t)cc0 * 512 + n] + w * embed[(size_t)cc1 * 512 + n];
                float val = acch[tm][tn][reg] + accx[tm][tn][reg] * (1.0f / 4096.0f);
                size_t off = (size_t)m * 512 + n;
                float r2 = resid[off] - (0.5f * h + 0.5f * (val + bias[n]));
                if (last) out[off] = x[off] - r2;
                else resid[off] = r2;
            }
        }
}

extern "C" void kernel_launch(void* const* d_in, const int* in_sizes, int n_in,
                              void* d_out, int out_size, void* d_ws, size_t ws_size,
                              hipStream_t stream) {
    const float* x     = (const float*)d_in[0];
    const float* embed = (const float*)d_in[1];
    const float* pw    = (const float*)d_in[2];
    const float* pb    = (const float*)d_in[3];
    float* out = (float*)d_out;

    // ws layout (floats), ~54.1 MB total:
    // resid 16MB | U 16MB (zh/zl halves; u<=12.6MB aliases after refine) |
    // ehi/elo 8MB | Wt2 hi/lo 12MB | esq 16KB | minbuf 64KB | cnt 32KB | cand 2MB
    float* resid = (float*)d_ws;
    float* Ubase = resid + 4194304;
    _Float16* zh = (_Float16*)Ubase;
    _Float16* zl = zh + 4194304;
    float* u = Ubase;
    _Float16* ehi = (_Float16*)(Ubase + 4194304);
    _Float16* elo = ehi + 2097152;
    _Float16* whi = elo + 2097152;
    _Float16* wlo = whi + 3145728;
    float* esq = (float*)(wlo + 3145728);
    unsigned long long* minbuf = (unsigned long long*)(esq + 4096);
    unsigned int* cntb = (unsigned int*)(minbuf + 8192);
    unsigned long long* cand = (unsigned long long*)(cntb + 8192);

    k_esq<<<1024, 256, 0, stream>>>(embed, esq);
    k_split_embed<<<2048, 256, 0, stream>>>(embed, ehi, elo);
    k_split_w<<<12288, 256, 0, stream>>>(pw, whi, wlo);
    k_copy<<<4096, 256, 0, stream>>>(x, resid);

    const int SCv[10] = {1, 2, 4, 8, 16, 32, 64, 128, 256, 512};
    // PHI_IDX with float64-ulp tie-breaks at si=2 and si=7 (verified round 2)
    const int PIv[10] = {0, 0, 1, 1, 1, 2, 2, 3, 3, 3};
    for (int si = 0; si < 10; ++si) {
        int s = SCv[si];
        int M = 16 * s;
        int kp = PIv[si];
        int lg = __builtin_ctz((unsigned)s);
        float scale = (float)s / 512.0f;
        k_zmean<<<(M * 512) / 256, 256, 0, stream>>>(resid, zh, zl, s, lg);
        (void)hipMemsetAsync(minbuf, 0xFF, (size_t)M * 8, stream);
        (void)hipMemsetAsync(cntb, 0, (size_t)M * 4, stream);
        k_dist1<<<dim3((M + 127) / 128, 32), 256, 0, stream>>>(zh, ehi, esq, minbuf, cntb, cand, M);
        k_refine<<<(M + 3) / 4, 256, 0, stream>>>(zh, zl, embed, cand, cntb, minbuf, M);
        if (s <= 128) {
            k_phi<<<dim3((M + 127) / 128, 12), 256, 0, stream>>>(ehi, elo,
                    whi + (size_t)kp * 1536 * 512, wlo + (size_t)kp * 1536 * 512, minbuf, u, M);
            k_combine<<<4096, 256, 0, stream>>>(u, embed, minbuf, pb + kp * 512, resid, s, scale);
        } else {
            k_conv<<<dim3(128, 4), 256, 0, stream>>>(ehi, elo, embed,
                    whi + (size_t)kp * 1536 * 512, wlo + (size_t)kp * 1536 * 512,
                    pb + kp * 512, minbuf, resid, s, scale, x, out, si == 9 ? 1 : 0);
        }
    }
}

// Round 5
// 945.314 us; speedup vs baseline: 1.1408x; 1.0206x over previous
//
#include <hip/hip_runtime.h>

// Multiscale Residual VQ (VAR-style), MI355X gfx950.
// Round 10:
//   - k_prep_q: materialize q[b,t] = lerp(embed[c0],embed[c1],w) -> split qh/ql
//     (bit-identical split2(lerp) to old in-loop path; s=512 w=0 -> split2(embed)).
//   - k_conv rebuilt as dist1-style async GEMM: global_load_lds w16, pre-swizzled
//     source + swizzled read (involution), double-buffered 2-phase, ONE barrier
//     per K-step, 64x64 tiles, grid (128,8)=1024 blocks = 4/CU, 32KB LDS.
//     A rows = qh/ql (contiguous, tap-shifted; OOB taps -> 64B zero row).
//     K order (tap-major) unchanged -> conv accumulation bit-identical.
//   - minbuf/cnt clears fused into k_zmean (-20 launches); k_copy dropped
//     (si=0 reads x directly in zmean/combine).
// dist1/refine/phi/combine cores unchanged from round 9.

#define ND 512
#define NCB 4096
#define CAP 32
#define DELTA 0.5f

typedef _Float16 half8v __attribute__((ext_vector_type(8)));
typedef float floatx4 __attribute__((ext_vector_type(4)));

struct HL { _Float16 h, l; };

__device__ __forceinline__ HL split2(float v) {
    HL r;
    r.h = (_Float16)v;
    r.l = (_Float16)((v - (float)r.h) * 4096.0f);
    return r;
}

__device__ __forceinline__ unsigned long long pack_dist(float d, int n) {
    unsigned u = __float_as_uint(d);
    u = (u & 0x80000000u) ? ~u : (u | 0x80000000u);   // monotone total order
    return ((unsigned long long)u << 32) | (unsigned)n; // tie -> lowest idx
}

__device__ __forceinline__ float unpack_dist(unsigned long long p) {
    unsigned u = (unsigned)(p >> 32);
    u = (u & 0x80000000u) ? (u & 0x7fffffffu) : ~u;
    return __uint_as_float(u);
}

// async global->LDS, 16B per lane; LDS dest = wave-uniform base + lane*16
__device__ __forceinline__ void gl2lds16(const _Float16* g, _Float16* l) {
    __builtin_amdgcn_global_load_lds(
        (const __attribute__((address_space(1))) unsigned int*)g,
        (__attribute__((address_space(3))) unsigned int*)l, 16, 0, 0);
}

// e_sq[c] = sum_d embed[c,d]^2, fp64 accumulate
__global__ __launch_bounds__(256) void k_esq(const float* __restrict__ embed,
                                             float* __restrict__ esq) {
    int c = blockIdx.x * 4 + (threadIdx.x >> 6);
    int lane = threadIdx.x & 63;
    const float* row = embed + (size_t)c * ND;
    double acc = 0.0;
#pragma unroll
    for (int i = 0; i < ND / 64; ++i) {
        float v = row[lane + i * 64];
        acc += (double)v * (double)v;
    }
#pragma unroll
    for (int off = 32; off > 0; off >>= 1) acc += __shfl_down(acc, off, 64);
    if (lane == 0) esq[c] = (float)acc;
}

// embed -> ehi/elo (4096x512 halves)
__global__ __launch_bounds__(256) void k_split_embed(const float* __restrict__ embed,
        _Float16* __restrict__ eh, _Float16* __restrict__ el) {
    int gid = blockIdx.x * 256 + threadIdx.x;       // 524288 float4s
    float4 v = ((const float4*)embed)[gid];
    HL a = split2(v.x), b = split2(v.y), c = split2(v.z), d = split2(v.w);
    _Float16* ph = eh + (size_t)gid * 4;
    _Float16* pl = el + (size_t)gid * 4;
    ph[0] = a.h; ph[1] = b.h; ph[2] = c.h; ph[3] = d.h;
    pl[0] = a.l; pl[1] = b.l; pl[2] = c.l; pl[3] = d.l;
}

// Wt2[kp][tap*512+dout][din] hi/lo from pw[kp][dout][din][tap]; output-indexed
__global__ __launch_bounds__(256) void k_split_w(const float* __restrict__ pw,
        _Float16* __restrict__ wh, _Float16* __restrict__ wl) {
    int gid = blockIdx.x * 256 + threadIdx.x;       // 4*1536*512 = 3,145,728
    int din = gid & 511;
    int nn = (gid >> 9) % 1536;
    int kp = gid / (512 * 1536);
    int tap = nn >> 9;
    int dout = nn & 511;
    float v = pw[(((size_t)(kp * 512 + dout) * 512) + din) * 3 + tap];
    HL r = split2(v);
    wh[gid] = r.h;
    wl[gid] = r.l;
}

// z[b,j,d] = block mean of src (fp64 acc) -> split halves zh/zl; also clears
// minbuf/cnt for this scale (fused, saves 2 memset launches per scale)
__global__ __launch_bounds__(256) void k_zmean(const float* __restrict__ src,
        _Float16* __restrict__ zh, _Float16* __restrict__ zl,
        unsigned long long* __restrict__ minbuf, unsigned int* __restrict__ cnt,
        int s, int lg, int M) {
    int gid = blockIdx.x * 256 + threadIdx.x;       // 16*s*512 threads
    if (gid < M) { minbuf[gid] = ~0ull; cnt[gid] = 0u; }
    int d = gid & 511;
    int j = (gid >> 9) & (s - 1);
    int b = gid >> (9 + lg);
    int r = 512 >> lg;
    const float* p = src + ((size_t)((b << 9) + (j << (9 - lg))) << 9) + d;
    double acc = 0.0;
#pragma unroll 4
    for (int m = 0; m < r; ++m) acc += (double)p[(size_t)m * ND];
    float v = (float)(acc * (1.0 / (double)r));
    HL hl = split2(v);
    zh[gid] = hl.h;
    zl[gid] = hl.l;
}

// ---------------- dist pass 1: hh-only GEMM, 128x128 block, 2x2 waves ----------------
__global__ __launch_bounds__(256, 4) void k_dist1(const _Float16* __restrict__ zh,
        const _Float16* __restrict__ eh, const float* __restrict__ esq,
        unsigned long long* __restrict__ minbuf, unsigned int* __restrict__ cnt,
        unsigned long long* __restrict__ cand, int M) {
    __shared__ _Float16 smem[2][2][4096] __attribute__((aligned(16)));  // 32 KB
    // epilogue aliases (live only after the main loop's trailing barrier):
    unsigned long long (*packs)[2] = reinterpret_cast<unsigned long long(*)[2]>(&smem[0][0][0]); // 2 KB
    float* Tlds = reinterpret_cast<float*>(reinterpret_cast<char*>(&smem[0][0][0]) + 2048);      // 512 B
    int tid = threadIdx.x;
    int lane = tid & 63, wave = tid >> 6;
    int wm = wave >> 1, wn = wave & 1;
    int quad = lane >> 4, l15 = lane & 15;
    int m0 = blockIdx.x * 128, n0 = blockIdx.y * 128;

    int slot = lane & 3;
    int r0 = wave * 32 + (lane >> 2);
    int r1 = r0 + 16;
    int sc0 = (slot ^ ((r0 >> 1) & 3)) << 3;    // swizzled source col (halves)
    int sc1 = (slot ^ ((r1 >> 1) & 3)) << 3;
    int a0 = m0 + r0; if (a0 >= M) a0 = M - 1;
    int a1 = m0 + r1; if (a1 >= M) a1 = M - 1;
    const _Float16* gA0 = zh + (size_t)a0 * 512 + sc0;
    const _Float16* gA1 = zh + (size_t)a1 * 512 + sc1;
    const _Float16* gB0 = eh + (size_t)(n0 + r0) * 512 + sc0;
    const _Float16* gB1 = eh + (size_t)(n0 + r1) * 512 + sc1;
    int ld0 = wave * 1024, ld1 = ld0 + 512;

    int cslot = (quad ^ ((l15 >> 1) & 3)) << 3;
    int rbA = (wm * 64 + l15) * 32 + cslot;
    int rbB = (wn * 64 + l15) * 32 + cslot;

#define STG(buf, kb) do { \
    gl2lds16(gA0 + (kb), &smem[buf][0][ld0]); \
    gl2lds16(gA1 + (kb), &smem[buf][0][ld1]); \
    gl2lds16(gB0 + (kb), &smem[buf][1][ld0]); \
    gl2lds16(gB1 + (kb), &smem[buf][1][ld1]); \
} while (0)

    floatx4 acc[4][4];
#pragma unroll
    for (int i = 0; i < 4; ++i)
#pragma unroll
        for (int j = 0; j < 4; ++j)
#pragma unroll
            for (int r = 0; r < 4; ++r) acc[i][j][r] = 0.f;

    STG(0, 0);
    __syncthreads();
    int cur = 0;
    for (int it = 0; it < 16; ++it) {
        if (it < 15) STG(cur ^ 1, (it + 1) * 32);
        const _Float16* sA = &smem[cur][0][0];
        const _Float16* sB = &smem[cur][1][0];
        half8v af[4], bf[4];
#pragma unroll
        for (int tm = 0; tm < 4; ++tm) af[tm] = *(const half8v*)&sA[rbA + tm * 512];
#pragma unroll
        for (int tn = 0; tn < 4; ++tn) bf[tn] = *(const half8v*)&sB[rbB + tn * 512];
#pragma unroll
        for (int tm = 0; tm < 4; ++tm)
#pragma unroll
            for (int tn = 0; tn < 4; ++tn)
                acc[tm][tn] = __builtin_amdgcn_mfma_f32_16x16x32_f16(af[tm], bf[tn], acc[tm][tn], 0, 0, 0);
        __syncthreads();
        cur ^= 1;
    }
#undef STG
    float es[4];
#pragma unroll
    for (int tn = 0; tn < 4; ++tn) es[tn] = esq[n0 + wn * 64 + tn * 16 + l15];
    // loop 1: per-m block-min
#pragma unroll
    for (int tm = 0; tm < 4; ++tm)
#pragma unroll
        for (int reg = 0; reg < 4; ++reg) {
            unsigned long long best = ~0ull;
#pragma unroll
            for (int tn = 0; tn < 4; ++tn) {
                float dd = fmaf(-2.f, acc[tm][tn][reg], es[tn]);
                int n = n0 + wn * 64 + tn * 16 + l15;
                unsigned long long p = pack_dist(dd, n);
                best = p < best ? p : best;
            }
#pragma unroll
            for (int off = 1; off < 16; off <<= 1) {
                unsigned long long q = __shfl_xor(best, off, 64);
                best = q < best ? q : best;
            }
            if (l15 == 0) packs[wm * 64 + tm * 16 + quad * 4 + reg][wn] = best;
        }
    __syncthreads();
    if (tid < 128) {
        float T = -1e30f;
        int m = m0 + tid;
        if (m < M) {
            unsigned long long b0 = packs[tid][0], b1 = packs[tid][1];
            unsigned long long bm = b0 < b1 ? b0 : b1;
            unsigned long long old = atomicMin(&minbuf[m], bm);
            unsigned long long g = old < bm ? old : bm;
            T = unpack_dist(g) + DELTA;
        }
        Tlds[tid] = T;
    }
    __syncthreads();
    // loop 2: append qualifying candidates (re-read global min -> tight T)
#pragma unroll
    for (int tm = 0; tm < 4; ++tm)
#pragma unroll
        for (int reg = 0; reg < 4; ++reg) {
            int row = wm * 64 + tm * 16 + quad * 4 + reg;
            int m = m0 + row;
            float T = Tlds[row];
            if (m < M) {
#pragma unroll
                for (int tn = 0; tn < 4; ++tn) {
                    float dd = fmaf(-2.f, acc[tm][tn][reg], es[tn]);
                    if (dd <= T) {
                        // refresh threshold from global (monotone-decreasing ->
                        // any stale read is a SAFE (>= final) threshold)
                        float Tf = unpack_dist(minbuf[m]) + DELTA;
                        if (dd <= Tf) {
                            int n = n0 + wn * 64 + tn * 16 + l15;
                            unsigned slotc = atomicAdd(&cnt[m], 1u);
                            if (slotc < CAP) cand[(size_t)m * CAP + slotc] = pack_dist(dd, n);
                        }
                    }
                }
            }
        }
}

// ---------------- dist pass 2: fp64-exact refine over appended candidates ----------------
__global__ __launch_bounds__(256) void k_refine(const _Float16* __restrict__ zh,
        const _Float16* __restrict__ zl, const float* __restrict__ embed,
        const unsigned long long* __restrict__ cand, const unsigned int* __restrict__ cnt,
        unsigned long long* __restrict__ minbuf, int M) {
    int lane = threadIdx.x & 63, wave = threadIdx.x >> 6;
    int m = blockIdx.x * 4 + wave;
    if (m >= M) return;
    float zr[8];
    const _Float16* ph = zh + (size_t)m * 512 + lane * 8;
    const _Float16* pl = zl + (size_t)m * 512 + lane * 8;
#pragma unroll
    for (int i = 0; i < 8; ++i)
        zr[i] = (float)ph[i] + (float)pl[i] * (1.0f / 4096.0f);
    unsigned c = cnt[m];
    float gd = unpack_dist(minbuf[m]) + DELTA;
    double bestD = 1e300;
    int bestI = 0x7fffffff;
    if (c <= CAP) {
        for (unsigned j = 0; j < c; ++j) {
            unsigned long long p = cand[(size_t)m * CAP + j];
            float d = unpack_dist(p);
            if (d <= gd) {
                int idx = (int)(unsigned)p;
                const float* e = embed + (size_t)idx * 512 + lane * 8;
                double s = 0.0;
#pragma unroll
                for (int i = 0; i < 8; ++i) {
                    double df = (double)zr[i] - (double)e[i];
                    s += df * df;
                }
#pragma unroll
                for (int off = 32; off > 0; off >>= 1) s += __shfl_down(s, off, 64);
                if (lane == 0) {
                    if (s < bestD || (s == bestD && idx < bestI)) { bestD = s; bestI = idx; }
                }
            }
        }
    } else {
        // overflow fallback (never expected): exact scan of all codes
        for (int idx = 0; idx < NCB; ++idx) {
            const float* e = embed + (size_t)idx * 512 + lane * 8;
            double s = 0.0;
#pragma unroll
            for (int i = 0; i < 8; ++i) {
                double df = (double)zr[i] - (double)e[i];
                s += df * df;
            }
#pragma unroll
            for (int off = 32; off > 0; off >>= 1) s += __shfl_down(s, off, 64);
            if (lane == 0) {
                if (s < bestD) { bestD = s; bestI = idx; }
            }
        }
    }
    if (lane == 0) minbuf[m] = (unsigned long long)(unsigned)bestI;
}

// ---------------- phi: u[m][tap*512+dout] = (W_tap q_m)[dout], m = b*s+j ----------------
__global__ __launch_bounds__(256, 2) void k_phi(const _Float16* __restrict__ eh,
        const _Float16* __restrict__ el, const _Float16* __restrict__ wh,
        const _Float16* __restrict__ wl, const unsigned long long* __restrict__ minbuf,
        float* __restrict__ u, int M) {
    __shared__ _Float16 smem[2][4][4096] __attribute__((aligned(16)));  // 64KB exactly
    int* idxs = reinterpret_cast<int*>(&smem[0][0][0]);
    int tid = threadIdx.x;
    int lane = tid & 63, wave = tid >> 6;
    int wm = wave >> 1, wn = wave & 1;
    int quad = lane >> 4, l15 = lane & 15;
    int m0 = blockIdx.x * 128, n0 = blockIdx.y * 128;
    if (tid < 128) {
        int m = m0 + tid; if (m >= M) m = M - 1;
        idxs[tid] = (int)(unsigned)minbuf[m];
    }
    __syncthreads();

    int slot = lane & 3;
    int r0 = wave * 32 + (lane >> 2);
    int r1 = r0 + 16;
    int sc0 = (slot ^ ((r0 >> 1) & 3)) << 3;
    int sc1 = (slot ^ ((r1 >> 1) & 3)) << 3;
    int code0 = idxs[r0];
    int code1 = idxs[r1];
    __syncthreads();   // all waves done reading idxs before DMA overwrites smem
    const _Float16* gA0h = eh + (size_t)code0 * 512 + sc0;
    const _Float16* gA1h = eh + (size_t)code1 * 512 + sc1;
    const _Float16* gA0l = el + (size_t)code0 * 512 + sc0;
    const _Float16* gA1l = el + (size_t)code1 * 512 + sc1;
    const _Float16* gB0h = wh + (size_t)(n0 + r0) * 512 + sc0;
    const _Float16* gB1h = wh + (size_t)(n0 + r1) * 512 + sc1;
    const _Float16* gB0l = wl + (size_t)(n0 + r0) * 512 + sc0;
    const _Float16* gB1l = wl + (size_t)(n0 + r1) * 512 + sc1;
    int ld0 = wave * 1024;
    int ld1 = ld0 + 512;

    int cslot = (quad ^ ((l15 >> 1) & 3)) << 3;
    int rbA = (wm * 64 + l15) * 32 + cslot;
    int rbB = (wn * 64 + l15) * 32 + cslot;

#define STAGE_P(buf, kb) do { \
    gl2lds16(gA0h + (kb), &smem[buf][0][ld0]); \
    gl2lds16(gA1h + (kb), &smem[buf][0][ld1]); \
    gl2lds16(gA0l + (kb), &smem[buf][1][ld0]); \
    gl2lds16(gA1l + (kb), &smem[buf][1][ld1]); \
    gl2lds16(gB0h + (kb), &smem[buf][2][ld0]); \
    gl2lds16(gB1h + (kb), &smem[buf][2][ld1]); \
    gl2lds16(gB0l + (kb), &smem[buf][3][ld0]); \
    gl2lds16(gB1l + (kb), &smem[buf][3][ld1]); \
} while (0)

    floatx4 acch[4][4], accx[4][4];
#pragma unroll
    for (int i = 0; i < 4; ++i)
#pragma unroll
        for (int j = 0; j < 4; ++j)
#pragma unroll
            for (int r = 0; r < 4; ++r) { acch[i][j][r] = 0.f; accx[i][j][r] = 0.f; }

    STAGE_P(0, 0);
    __syncthreads();
    int cur = 0;
    for (int it = 0; it < 16; ++it) {
        if (it < 15) STAGE_P(cur ^ 1, (it + 1) * 32);
        const _Float16* sAh = &smem[cur][0][0];
        const _Float16* sAl = &smem[cur][1][0];
        const _Float16* sBh = &smem[cur][2][0];
        const _Float16* sBl = &smem[cur][3][0];
        half8v afh[4], afl[4], bfh[4], bfl[4];
#pragma unroll
        for (int tm = 0; tm < 4; ++tm) {
            afh[tm] = *(const half8v*)&sAh[rbA + tm * 512];
            afl[tm] = *(const half8v*)&sAl[rbA + tm * 512];
        }
#pragma unroll
        for (int tn = 0; tn < 4; ++tn) {
            bfh[tn] = *(const half8v*)&sBh[rbB + tn * 512];
            bfl[tn] = *(const half8v*)&sBl[rbB + tn * 512];
        }
#pragma unroll
        for (int tm = 0; tm < 4; ++tm)
#pragma unroll
            for (int tn = 0; tn < 4; ++tn) {
                acch[tm][tn] = __builtin_amdgcn_mfma_f32_16x16x32_f16(afh[tm], bfh[tn], acch[tm][tn], 0, 0, 0);
                accx[tm][tn] = __builtin_amdgcn_mfma_f32_16x16x32_f16(afh[tm], bfl[tn], accx[tm][tn], 0, 0, 0);
                accx[tm][tn] = __builtin_amdgcn_mfma_f32_16x16x32_f16(afl[tm], bfh[tn], accx[tm][tn], 0, 0, 0);
            }
        __syncthreads();
        cur ^= 1;
    }
#undef STAGE_P
#pragma unroll
    for (int tm = 0; tm < 4; ++tm)
#pragma unroll
        for (int reg = 0; reg < 4; ++reg) {
            int m = m0 + wm * 64 + tm * 16 + quad * 4 + reg;
            if (m < M) {
#pragma unroll
                for (int tn = 0; tn < 4; ++tn) {
                    int n = n0 + wn * 64 + tn * 16 + l15;
                    u[(size_t)m * 1536 + n] = acch[tm][tn][reg] + accx[tm][tn][reg] * (1.0f / 4096.0f);
                }
            }
        }
}

// combine (s<=128): resid = rsrc - (0.5*h + 0.5*(conv+bias)); h = lerp(embed[idx]),
// conv[t] = sum_tap lerp of u[.][tap] at t' = t+tap-1 ; rsrc = x at si=0
__global__ __launch_bounds__(256) void k_combine(const float* __restrict__ u,
        const float* __restrict__ embed, const unsigned long long* __restrict__ minbuf,
        const float* __restrict__ bias, const float* __restrict__ rsrc,
        float* __restrict__ resid, int s, float scale) {
    int tid = threadIdx.x;
    int m = blockIdx.x * 2 + (tid >> 7);
    int d4 = (tid & 127) << 2;
    int b = m >> 9, t = m & 511;
    int bs = b * s;
    float4 bi = *(const float4*)(bias + d4);
    float uu = ((float)t + 0.5f) * scale - 0.5f;
    float fl = floorf(uu);
    float w = uu - fl;
    int i0 = (int)fl, i1 = i0 + 1;
    i0 = min(max(i0, 0), s - 1);
    i1 = min(max(i1, 0), s - 1);
    int c0 = (int)(unsigned)minbuf[bs + i0];
    int c1 = (int)(unsigned)minbuf[bs + i1];
    float4 e0 = *(const float4*)(embed + (size_t)c0 * 512 + d4);
    float4 e1 = *(const float4*)(embed + (size_t)c1 * 512 + d4);
    float om = 1.0f - w;
    float4 h4;
    h4.x = om * e0.x + w * e1.x; h4.y = om * e0.y + w * e1.y;
    h4.z = om * e0.z + w * e1.z; h4.w = om * e0.w + w * e1.w;
    float4 conv = make_float4(0.f, 0.f, 0.f, 0.f);
#pragma unroll
    for (int tap = 0; tap < 3; ++tap) {
        int tt = t + tap - 1;
        if (tt >= 0 && tt < 512) {
            float uu2 = ((float)tt + 0.5f) * scale - 0.5f;
            float fl2 = floorf(uu2);
            float w2 = uu2 - fl2;
            int j0 = (int)fl2, j1 = j0 + 1;
            j0 = min(max(j0, 0), s - 1);
            j1 = min(max(j1, 0), s - 1);
            float4 a4 = *(const float4*)(u + (size_t)(bs + j0) * 1536 + tap * 512 + d4);
            float4 b4 = *(const float4*)(u + (size_t)(bs + j1) * 1536 + tap * 512 + d4);
            float ow = 1.0f - w2;
            conv.x += ow * a4.x + w2 * b4.x;
            conv.y += ow * a4.y + w2 * b4.y;
            conv.z += ow * a4.z + w2 * b4.z;
            conv.w += ow * a4.w + w2 * b4.w;
        }
    }
    size_t off = (size_t)m * 512 + d4;
    float4 rv = *(const float4*)(rsrc + off);
    rv.x -= 0.5f * h4.x + 0.5f * (conv.x + bi.x);
    rv.y -= 0.5f * h4.y + 0.5f * (conv.y + bi.y);
    rv.z -= 0.5f * h4.z + 0.5f * (conv.z + bi.z);
    rv.w -= 0.5f * h4.w + 0.5f * (conv.w + bi.w);
    *(float4*)(resid + off) = rv;
}

// q[b,t] = lerp(embed[c0],embed[c1],w) -> split qh/ql (8192 rows x 512)
// Bit-identical split2(lerp) to the old in-conv staging; s=512 -> split2(embed).
__global__ __launch_bounds__(256) void k_prep_q(const float* __restrict__ embed,
        const unsigned long long* __restrict__ minbuf, _Float16* __restrict__ qh,
        _Float16* __restrict__ ql, int s, float scale, _Float16* __restrict__ zbuf) {
    int gid = blockIdx.x * 256 + threadIdx.x;   // 524288 threads, 8 halves each
    if (gid < 32) zbuf[gid] = (_Float16)0.f;    // 64B zero row (idempotent)
    int d8 = (gid & 63) << 3;
    int m = gid >> 6;          // b*512 + t
    int b = m >> 9, t = m & 511;
    int bs = b * s;
    float uu = ((float)t + 0.5f) * scale - 0.5f;
    float fl = floorf(uu);
    float w = uu - fl;
    int i0 = (int)fl, i1 = i0 + 1;
    i0 = min(max(i0, 0), s - 1);
    i1 = min(max(i1, 0), s - 1);
    int c0 = (int)(unsigned)minbuf[bs + i0];
    int c1 = (int)(unsigned)minbuf[bs + i1];
    const float* p0 = embed + (size_t)c0 * 512 + d8;
    const float* p1 = embed + (size_t)c1 * 512 + d8;
    float ow = 1.0f - w;
    half8v hh8, ll8;
#pragma unroll
    for (int q = 0; q < 8; ++q) {
        float v = ow * p0[q] + w * p1[q];
        HL hl = split2(v);
        hh8[q] = hl.h; ll8[q] = hl.l;
    }
    *(half8v*)(qh + (size_t)m * 512 + d8) = hh8;
    *(half8v*)(ql + (size_t)m * 512 + d8) = ll8;
}

// direct conv (s in {256,512}): GEMM [8192 x 1536(tap,din)] x [1536 x 512(dout)]
// A rows = qh/ql at t' = t+tap-1 (zero row if OOB); B = Wt2 rows.
// dist1-style async staging, 64x64 tiles, grid (128,8)=1024 blocks.
// epilogue: r2 = resid - (0.5*h + 0.5*(conv+bias)); last ? out = x - r2 : resid = r2
__global__ __launch_bounds__(256, 4) void k_conv(const _Float16* __restrict__ qh,
        const _Float16* __restrict__ ql, const float* __restrict__ embed,
        const _Float16* __restrict__ wh, const _Float16* __restrict__ wl,
        const float* __restrict__ bias, const unsigned long long* __restrict__ minbuf,
        float* __restrict__ resid, int s, float scale,
        const float* __restrict__ x, float* __restrict__ out, int last,
        const _Float16* __restrict__ zbuf) {
    __shared__ _Float16 smem[2][4][2048] __attribute__((aligned(16))); // 32 KB
    int tid = threadIdx.x;
    int lane = tid & 63, wave = tid >> 6;
    int wm = wave >> 1, wn = wave & 1;
    int quad = lane >> 4, l15 = lane & 15;
    int m0 = blockIdx.x * 64, n0 = blockIdx.y * 64;
    int b = m0 >> 9, t0 = m0 & 511;
    // staging: wave w covers LDS rows w*16..w*16+15; lane -> (row, 16B slot)
    int row = wave * 16 + (lane >> 2);
    int slot = lane & 3;
    int ssw = (slot ^ ((row >> 1) & 3)) << 3;   // swizzled source col (halves)
    int ld = wave * 512;                         // dest: wave-uniform + lane*16B

#define STG_C(buf, itv) do { \
    int tap_ = (itv) >> 4; \
    int dk_ = ((itv) & 15) << 5; \
    int tp_ = t0 + row + tap_ - 1; \
    bool v_ = ((unsigned)tp_ < 512u); \
    size_t ao_ = ((size_t)((b << 9) + (v_ ? tp_ : 0)) << 9) + dk_ + ssw; \
    const _Float16* aH_ = v_ ? qh + ao_ : zbuf + ssw; \
    const _Float16* aL_ = v_ ? ql + ao_ : zbuf + ssw; \
    size_t bo_ = ((size_t)((tap_ << 9) + n0 + row) << 9) + dk_ + ssw; \
    gl2lds16(aH_, &smem[buf][0][ld]); \
    gl2lds16(aL_, &smem[buf][1][ld]); \
    gl2lds16(wh + bo_, &smem[buf][2][ld]); \
    gl2lds16(wl + bo_, &smem[buf][3][ld]); \
} while (0)

    floatx4 acch[2][2], accx[2][2];
#pragma unroll
    for (int i = 0; i < 2; ++i)
#pragma unroll
        for (int j = 0; j < 2; ++j)
#pragma unroll
            for (int r = 0; r < 4; ++r) { acch[i][j][r] = 0.f; accx[i][j][r] = 0.f; }

    STG_C(0, 0);
    __syncthreads();
    int cur = 0;
    for (int it = 0; it < 48; ++it) {
        if (it < 47) STG_C(cur ^ 1, it + 1);
        const _Float16* sAh = &smem[cur][0][0];
        const _Float16* sAl = &smem[cur][1][0];
        const _Float16* sBh = &smem[cur][2][0];
        const _Float16* sBl = &smem[cur][3][0];
        half8v afh[2], afl[2], bfh[2], bfl[2];
#pragma unroll
        for (int tm = 0; tm < 2; ++tm) {
            int rA = wm * 32 + tm * 16 + l15;
            int cs = (quad ^ ((rA >> 1) & 3)) << 3;
            afh[tm] = *(const half8v*)&sAh[rA * 32 + cs];
            afl[tm] = *(const half8v*)&sAl[rA * 32 + cs];
        }
#pragma unroll
        for (int tn = 0; tn < 2; ++tn) {
            int rB = wn * 32 + tn * 16 + l15;
            int cs = (quad ^ ((rB >> 1) & 3)) << 3;
            bfh[tn] = *(const half8v*)&sBh[rB * 32 + cs];
            bfl[tn] = *(const half8v*)&sBl[rB * 32 + cs];
        }
#pragma unroll
        for (int tm = 0; tm < 2; ++tm)
#pragma unroll
            for (int tn = 0; tn < 2; ++tn) {
                acch[tm][tn] = __builtin_amdgcn_mfma_f32_16x16x32_f16(afh[tm], bfh[tn], acch[tm][tn], 0, 0, 0);
                accx[tm][tn] = __builtin_amdgcn_mfma_f32_16x16x32_f16(afh[tm], bfl[tn], accx[tm][tn], 0, 0, 0);
                accx[tm][tn] = __builtin_amdgcn_mfma_f32_16x16x32_f16(afl[tm], bfh[tn], accx[tm][tn], 0, 0, 0);
            }
        __syncthreads();
        cur ^= 1;
    }
#undef STG_C
#pragma unroll
    for (int tm = 0; tm < 2; ++tm)
#pragma unroll
        for (int reg = 0; reg < 4; ++reg) {
            int rrow = wm * 32 + tm * 16 + quad * 4 + reg;
            int m = m0 + rrow;
            int t = t0 + rrow;
            float uu = ((float)t + 0.5f) * scale - 0.5f;
            float fl = floorf(uu);
            float w = uu - fl;
            int i0 = (int)fl, i1 = i0 + 1;
            i0 = min(max(i0, 0), s - 1);
            i1 = min(max(i1, 0), s - 1);
            int bs = b * s;
            int c0 = (int)(unsigned)minbuf[bs + i0];
            int c1 = (int)(unsigned)minbuf[bs + i1];
            float ow = 1.0f - w;
#pragma unroll
            for (int tn = 0; tn < 2; ++tn) {
                int n = n0 + wn * 32 + tn * 16 + l15;
                float h = ow * embed[(size_t)c0 * 512 + n] + w * embed[(size_t)c1 * 512 + n];
                float val = acch[tm][tn][reg] + accx[tm][tn][reg] * (1.0f / 4096.0f);
                size_t off = (size_t)m * 512 + n;
                float r2 = resid[off] - (0.5f * h + 0.5f * (val + bias[n]));
                if (last) out[off] = x[off] - r2;
                else resid[off] = r2;
            }
        }
}

extern "C" void kernel_launch(void* const* d_in, const int* in_sizes, int n_in,
                              void* d_out, int out_size, void* d_ws, size_t ws_size,
                              hipStream_t stream) {
    const float* x     = (const float*)d_in[0];
    const float* embed = (const float*)d_in[1];
    const float* pw    = (const float*)d_in[2];
    const float* pb    = (const float*)d_in[3];
    float* out = (float*)d_out;

    // ws layout (floats), ~54.1 MB total:
    // resid 16MB | U 16MB (zh/zl = qh/ql halves; u<=12.6MB aliases after refine) |
    // ehi/elo 8MB | Wt2 hi/lo 12MB | esq 16KB | minbuf 64KB | cnt 32KB | cand 2MB | zbuf 64B
    float* resid = (float*)d_ws;
    float* Ubase = resid + 4194304;
    _Float16* zh = (_Float16*)Ubase;            // also qh after refine (s>=256)
    _Float16* zl = zh + 4194304;                // also ql
    float* u = Ubase;
    _Float16* ehi = (_Float16*)(Ubase + 4194304);
    _Float16* elo = ehi + 2097152;
    _Float16* whi = elo + 2097152;
    _Float16* wlo = whi + 3145728;
    float* esq = (float*)(wlo + 3145728);
    unsigned long long* minbuf = (unsigned long long*)(esq + 4096);
    unsigned int* cntb = (unsigned int*)(minbuf + 8192);
    unsigned long long* cand = (unsigned long long*)(cntb + 8192);
    _Float16* zbuf = (_Float16*)(cand + 262144);

    k_esq<<<1024, 256, 0, stream>>>(embed, esq);
    k_split_embed<<<2048, 256, 0, stream>>>(embed, ehi, elo);
    k_split_w<<<12288, 256, 0, stream>>>(pw, whi, wlo);

    const int SCv[10] = {1, 2, 4, 8, 16, 32, 64, 128, 256, 512};
    // PHI_IDX with float64-ulp tie-breaks at si=2 and si=7 (verified round 2)
    const int PIv[10] = {0, 0, 1, 1, 1, 2, 2, 3, 3, 3};
    for (int si = 0; si < 10; ++si) {
        int s = SCv[si];
        int M = 16 * s;
        int kp = PIv[si];
        int lg = __builtin_ctz((unsigned)s);
        float scale = (float)s / 512.0f;
        const float* src = (si == 0) ? x : resid;
        k_zmean<<<(M * 512) / 256, 256, 0, stream>>>(src, zh, zl, minbuf, cntb, s, lg, M);
        k_dist1<<<dim3((M + 127) / 128, 32), 256, 0, stream>>>(zh, ehi, esq, minbuf, cntb, cand, M);
        k_refine<<<(M + 3) / 4, 256, 0, stream>>>(zh, zl, embed, cand, cntb, minbuf, M);
        if (s <= 128) {
            k_phi<<<dim3((M + 127) / 128, 12), 256, 0, stream>>>(ehi, elo,
                    whi + (size_t)kp * 1536 * 512, wlo + (size_t)kp * 1536 * 512, minbuf, u, M);
            k_combine<<<4096, 256, 0, stream>>>(u, embed, minbuf, pb + kp * 512, src, resid, s, scale);
        } else {
            k_prep_q<<<2048, 256, 0, stream>>>(embed, minbuf, zh, zl, s, scale, zbuf);
            k_conv<<<dim3(128, 8), 256, 0, stream>>>(zh, zl, embed,
                    whi + (size_t)kp * 1536 * 512, wlo + (size_t)kp * 1536 * 512,
                    pb + kp * 512, minbuf, resid, s, scale, x, out, si == 9 ? 1 : 0, zbuf);
        }
    }
}

// Round 6
// 838.275 us; speedup vs baseline: 1.2864x; 1.1277x over previous
//
#include <hip/hip_runtime.h>

// Multiscale Residual VQ (VAR-style), MI355X gfx950.
// Round 11: dist argmin candidates via DETERMINISTIC per-block top-2 (no atomics).
//   Round-10 dist1 epilogue generated 198 MB/dispatch of device-scope atomic/EA
//   traffic (atomicMin + per-candidate fresh minbuf reads + atomicAdd) = ~43 us
//   of the 81 us dispatch. New epilogue: per (m, n-block) keep (best, second)
//   via shuffle reduction, ONE plain 16B store -> 4 MB total, zero atomics.
//   Exactness: true argmin ejected from its block's top-2 only if 2 same-block
//   candidates beat it in approx dist (3 near-ties within fp16 eps in one
//   128-code block) - strictly rarer than round-10's raced DELTA scheme.
//   k_refine: gather 64 cands/m (1/lane), wave-min -> T, fp64-exact check on
//   ballot'd qualifiers (~1-3), tie -> lowest idx. minbuf now write-only by
//   refine (no init); cnt/cand buffers and zmean clears removed.
// GEMM cores (dist1/phi/conv), prep_q, combine unchanged from round 10.

#define ND 512
#define NCB 4096
#define DELTA 0.5f

typedef _Float16 half8v __attribute__((ext_vector_type(8)));
typedef float floatx4 __attribute__((ext_vector_type(4)));

struct HL { _Float16 h, l; };

__device__ __forceinline__ HL split2(float v) {
    HL r;
    r.h = (_Float16)v;
    r.l = (_Float16)((v - (float)r.h) * 4096.0f);
    return r;
}

__device__ __forceinline__ unsigned long long pack_dist(float d, int n) {
    unsigned u = __float_as_uint(d);
    u = (u & 0x80000000u) ? ~u : (u | 0x80000000u);   // monotone total order
    return ((unsigned long long)u << 32) | (unsigned)n; // tie -> lowest idx
}

__device__ __forceinline__ float unpack_dist(unsigned long long p) {
    unsigned u = (unsigned)(p >> 32);
    u = (u & 0x80000000u) ? (u & 0x7fffffffu) : ~u;
    return __uint_as_float(u);
}

// async global->LDS, 16B per lane; LDS dest = wave-uniform base + lane*16
__device__ __forceinline__ void gl2lds16(const _Float16* g, _Float16* l) {
    __builtin_amdgcn_global_load_lds(
        (const __attribute__((address_space(1))) unsigned int*)g,
        (__attribute__((address_space(3))) unsigned int*)l, 16, 0, 0);
}

// e_sq[c] = sum_d embed[c,d]^2, fp64 accumulate
__global__ __launch_bounds__(256) void k_esq(const float* __restrict__ embed,
                                             float* __restrict__ esq) {
    int c = blockIdx.x * 4 + (threadIdx.x >> 6);
    int lane = threadIdx.x & 63;
    const float* row = embed + (size_t)c * ND;
    double acc = 0.0;
#pragma unroll
    for (int i = 0; i < ND / 64; ++i) {
        float v = row[lane + i * 64];
        acc += (double)v * (double)v;
    }
#pragma unroll
    for (int off = 32; off > 0; off >>= 1) acc += __shfl_down(acc, off, 64);
    if (lane == 0) esq[c] = (float)acc;
}

// embed -> ehi/elo (4096x512 halves)
__global__ __launch_bounds__(256) void k_split_embed(const float* __restrict__ embed,
        _Float16* __restrict__ eh, _Float16* __restrict__ el) {
    int gid = blockIdx.x * 256 + threadIdx.x;       // 524288 float4s
    float4 v = ((const float4*)embed)[gid];
    HL a = split2(v.x), b = split2(v.y), c = split2(v.z), d = split2(v.w);
    _Float16* ph = eh + (size_t)gid * 4;
    _Float16* pl = el + (size_t)gid * 4;
    ph[0] = a.h; ph[1] = b.h; ph[2] = c.h; ph[3] = d.h;
    pl[0] = a.l; pl[1] = b.l; pl[2] = c.l; pl[3] = d.l;
}

// Wt2[kp][tap*512+dout][din] hi/lo from pw[kp][dout][din][tap]; output-indexed
__global__ __launch_bounds__(256) void k_split_w(const float* __restrict__ pw,
        _Float16* __restrict__ wh, _Float16* __restrict__ wl) {
    int gid = blockIdx.x * 256 + threadIdx.x;       // 4*1536*512 = 3,145,728
    int din = gid & 511;
    int nn = (gid >> 9) % 1536;
    int kp = gid / (512 * 1536);
    int tap = nn >> 9;
    int dout = nn & 511;
    float v = pw[(((size_t)(kp * 512 + dout) * 512) + din) * 3 + tap];
    HL r = split2(v);
    wh[gid] = r.h;
    wl[gid] = r.l;
}

// z[b,j,d] = block mean of src (fp64 acc) -> split halves zh/zl
__global__ __launch_bounds__(256) void k_zmean(const float* __restrict__ src,
        _Float16* __restrict__ zh, _Float16* __restrict__ zl, int s, int lg) {
    int gid = blockIdx.x * 256 + threadIdx.x;       // 16*s*512 threads
    int d = gid & 511;
    int j = (gid >> 9) & (s - 1);
    int b = gid >> (9 + lg);
    int r = 512 >> lg;
    const float* p = src + ((size_t)((b << 9) + (j << (9 - lg))) << 9) + d;
    double acc = 0.0;
#pragma unroll 4
    for (int m = 0; m < r; ++m) acc += (double)p[(size_t)m * ND];
    float v = (float)(acc * (1.0 / (double)r));
    HL hl = split2(v);
    zh[gid] = hl.h;
    zl[gid] = hl.l;
}

// ---------------- dist pass 1: hh-only GEMM, 128x128 block, 2x2 waves ----------------
// epilogue: per-(m, n-block) top-2 packed (dist,idx) -> bm2[m][32][2], no atomics
__global__ __launch_bounds__(256, 4) void k_dist1(const _Float16* __restrict__ zh,
        const _Float16* __restrict__ eh, const float* __restrict__ esq,
        unsigned long long* __restrict__ bm2, int M) {
    __shared__ _Float16 smem[2][2][4096] __attribute__((aligned(16)));  // 32 KB
    // epilogue alias (live only after the main loop's trailing barrier): 4 KB
    unsigned long long (*packs2)[2][2] =
        reinterpret_cast<unsigned long long(*)[2][2]>(&smem[0][0][0]);
    int tid = threadIdx.x;
    int lane = tid & 63, wave = tid >> 6;
    int wm = wave >> 1, wn = wave & 1;
    int quad = lane >> 4, l15 = lane & 15;
    int m0 = blockIdx.x * 128, n0 = blockIdx.y * 128;

    int slot = lane & 3;
    int r0 = wave * 32 + (lane >> 2);
    int r1 = r0 + 16;
    int sc0 = (slot ^ ((r0 >> 1) & 3)) << 3;    // swizzled source col (halves)
    int sc1 = (slot ^ ((r1 >> 1) & 3)) << 3;
    int a0 = m0 + r0; if (a0 >= M) a0 = M - 1;
    int a1 = m0 + r1; if (a1 >= M) a1 = M - 1;
    const _Float16* gA0 = zh + (size_t)a0 * 512 + sc0;
    const _Float16* gA1 = zh + (size_t)a1 * 512 + sc1;
    const _Float16* gB0 = eh + (size_t)(n0 + r0) * 512 + sc0;
    const _Float16* gB1 = eh + (size_t)(n0 + r1) * 512 + sc1;
    int ld0 = wave * 1024, ld1 = ld0 + 512;

    int cslot = (quad ^ ((l15 >> 1) & 3)) << 3;
    int rbA = (wm * 64 + l15) * 32 + cslot;
    int rbB = (wn * 64 + l15) * 32 + cslot;

#define STG(buf, kb) do { \
    gl2lds16(gA0 + (kb), &smem[buf][0][ld0]); \
    gl2lds16(gA1 + (kb), &smem[buf][0][ld1]); \
    gl2lds16(gB0 + (kb), &smem[buf][1][ld0]); \
    gl2lds16(gB1 + (kb), &smem[buf][1][ld1]); \
} while (0)

    floatx4 acc[4][4];
#pragma unroll
    for (int i = 0; i < 4; ++i)
#pragma unroll
        for (int j = 0; j < 4; ++j)
#pragma unroll
            for (int r = 0; r < 4; ++r) acc[i][j][r] = 0.f;

    STG(0, 0);
    __syncthreads();
    int cur = 0;
    for (int it = 0; it < 16; ++it) {
        if (it < 15) STG(cur ^ 1, (it + 1) * 32);
        const _Float16* sA = &smem[cur][0][0];
        const _Float16* sB = &smem[cur][1][0];
        half8v af[4], bf[4];
#pragma unroll
        for (int tm = 0; tm < 4; ++tm) af[tm] = *(const half8v*)&sA[rbA + tm * 512];
#pragma unroll
        for (int tn = 0; tn < 4; ++tn) bf[tn] = *(const half8v*)&sB[rbB + tn * 512];
#pragma unroll
        for (int tm = 0; tm < 4; ++tm)
#pragma unroll
            for (int tn = 0; tn < 4; ++tn)
                acc[tm][tn] = __builtin_amdgcn_mfma_f32_16x16x32_f16(af[tm], bf[tn], acc[tm][tn], 0, 0, 0);
        __syncthreads();
        cur ^= 1;
    }
#undef STG
    float es[4];
#pragma unroll
    for (int tn = 0; tn < 4; ++tn) es[tn] = esq[n0 + wn * 64 + tn * 16 + l15];
    // per-(m, half-block) top-2 reduction, zero atomics
#pragma unroll
    for (int tm = 0; tm < 4; ++tm)
#pragma unroll
        for (int reg = 0; reg < 4; ++reg) {
            unsigned long long b = ~0ull, sd = ~0ull;
#pragma unroll
            for (int tn = 0; tn < 4; ++tn) {
                float dd = fmaf(-2.f, acc[tm][tn][reg], es[tn]);
                int n = n0 + wn * 64 + tn * 16 + l15;
                unsigned long long p = pack_dist(dd, n);
                if (p < b) { sd = b; b = p; } else if (p < sd) sd = p;
            }
#pragma unroll
            for (int off = 1; off < 16; off <<= 1) {
                unsigned long long ob = __shfl_xor(b, off, 64);
                unsigned long long os = __shfl_xor(sd, off, 64);
                unsigned long long mx = b > ob ? b : ob;
                b = b < ob ? b : ob;
                unsigned long long mn2 = sd < os ? sd : os;
                sd = mx < mn2 ? mx : mn2;
            }
            if (l15 == 0) {
                packs2[wm * 64 + tm * 16 + quad * 4 + reg][wn][0] = b;
                packs2[wm * 64 + tm * 16 + quad * 4 + reg][wn][1] = sd;
            }
        }
    __syncthreads();
    if (tid < 128) {
        unsigned long long b0 = packs2[tid][0][0], s0 = packs2[tid][0][1];
        unsigned long long b1 = packs2[tid][1][0], s1 = packs2[tid][1][1];
        unsigned long long b = b0 < b1 ? b0 : b1;
        unsigned long long mx = b0 > b1 ? b0 : b1;
        unsigned long long mn2 = s0 < s1 ? s0 : s1;
        unsigned long long sd = mx < mn2 ? mx : mn2;
        size_t idx = ((size_t)(m0 + tid) * 32 + blockIdx.y) * 2;
        bm2[idx] = b;
        bm2[idx + 1] = sd;
    }
}

// ---------------- dist pass 2: exact refine over 64 gathered candidates ----------------
__global__ __launch_bounds__(256) void k_refine(const _Float16* __restrict__ zh,
        const _Float16* __restrict__ zl, const float* __restrict__ embed,
        const unsigned long long* __restrict__ bm2,
        unsigned long long* __restrict__ minbuf, int M) {
    int lane = threadIdx.x & 63, wave = threadIdx.x >> 6;
    int m = blockIdx.x * 4 + wave;
    if (m >= M) return;
    float zr[8];
    const _Float16* ph = zh + (size_t)m * 512 + lane * 8;
    const _Float16* pl = zl + (size_t)m * 512 + lane * 8;
#pragma unroll
    for (int i = 0; i < 8; ++i)
        zr[i] = (float)ph[i] + (float)pl[i] * (1.0f / 4096.0f);
    unsigned long long p = bm2[(size_t)m * 64 + lane];
    unsigned long long mn = p;
#pragma unroll
    for (int off = 1; off < 64; off <<= 1) {
        unsigned long long q = __shfl_xor(mn, off, 64);
        mn = q < mn ? q : mn;
    }
    float T = unpack_dist(mn) + DELTA;
    unsigned long long mask = __ballot(unpack_dist(p) <= T);
    double bestD = 1e300;
    int bestI = 0x7fffffff;
    while (mask) {
        int bit = __ffsll((unsigned long long)mask) - 1;
        mask &= mask - 1;
        int idx = (int)(unsigned)__shfl(p, bit, 64);
        const float* e = embed + (size_t)idx * 512 + lane * 8;
        double s = 0.0;
#pragma unroll
        for (int i = 0; i < 8; ++i) {
            double df = (double)zr[i] - (double)e[i];
            s += df * df;
        }
#pragma unroll
        for (int off = 32; off > 0; off >>= 1) s += __shfl_down(s, off, 64);
        if (lane == 0) {
            if (s < bestD || (s == bestD && idx < bestI)) { bestD = s; bestI = idx; }
        }
    }
    if (lane == 0) minbuf[m] = (unsigned long long)(unsigned)bestI;
}

// ---------------- phi: u[m][tap*512+dout] = (W_tap q_m)[dout], m = b*s+j ----------------
__global__ __launch_bounds__(256, 2) void k_phi(const _Float16* __restrict__ eh,
        const _Float16* __restrict__ el, const _Float16* __restrict__ wh,
        const _Float16* __restrict__ wl, const unsigned long long* __restrict__ minbuf,
        float* __restrict__ u, int M) {
    __shared__ _Float16 smem[2][4][4096] __attribute__((aligned(16)));  // 64KB exactly
    int* idxs = reinterpret_cast<int*>(&smem[0][0][0]);
    int tid = threadIdx.x;
    int lane = tid & 63, wave = tid >> 6;
    int wm = wave >> 1, wn = wave & 1;
    int quad = lane >> 4, l15 = lane & 15;
    int m0 = blockIdx.x * 128, n0 = blockIdx.y * 128;
    if (tid < 128) {
        int m = m0 + tid; if (m >= M) m = M - 1;
        idxs[tid] = (int)(unsigned)minbuf[m];
    }
    __syncthreads();

    int slot = lane & 3;
    int r0 = wave * 32 + (lane >> 2);
    int r1 = r0 + 16;
    int sc0 = (slot ^ ((r0 >> 1) & 3)) << 3;
    int sc1 = (slot ^ ((r1 >> 1) & 3)) << 3;
    int code0 = idxs[r0];
    int code1 = idxs[r1];
    __syncthreads();   // all waves done reading idxs before DMA overwrites smem
    const _Float16* gA0h = eh + (size_t)code0 * 512 + sc0;
    const _Float16* gA1h = eh + (size_t)code1 * 512 + sc1;
    const _Float16* gA0l = el + (size_t)code0 * 512 + sc0;
    const _Float16* gA1l = el + (size_t)code1 * 512 + sc1;
    const _Float16* gB0h = wh + (size_t)(n0 + r0) * 512 + sc0;
    const _Float16* gB1h = wh + (size_t)(n0 + r1) * 512 + sc1;
    const _Float16* gB0l = wl + (size_t)(n0 + r0) * 512 + sc0;
    const _Float16* gB1l = wl + (size_t)(n0 + r1) * 512 + sc1;
    int ld0 = wave * 1024;
    int ld1 = ld0 + 512;

    int cslot = (quad ^ ((l15 >> 1) & 3)) << 3;
    int rbA = (wm * 64 + l15) * 32 + cslot;
    int rbB = (wn * 64 + l15) * 32 + cslot;

#define STAGE_P(buf, kb) do { \
    gl2lds16(gA0h + (kb), &smem[buf][0][ld0]); \
    gl2lds16(gA1h + (kb), &smem[buf][0][ld1]); \
    gl2lds16(gA0l + (kb), &smem[buf][1][ld0]); \
    gl2lds16(gA1l + (kb), &smem[buf][1][ld1]); \
    gl2lds16(gB0h + (kb), &smem[buf][2][ld0]); \
    gl2lds16(gB1h + (kb), &smem[buf][2][ld1]); \
    gl2lds16(gB0l + (kb), &smem[buf][3][ld0]); \
    gl2lds16(gB1l + (kb), &smem[buf][3][ld1]); \
} while (0)

    floatx4 acch[4][4], accx[4][4];
#pragma unroll
    for (int i = 0; i < 4; ++i)
#pragma unroll
        for (int j = 0; j < 4; ++j)
#pragma unroll
            for (int r = 0; r < 4; ++r) { acch[i][j][r] = 0.f; accx[i][j][r] = 0.f; }

    STAGE_P(0, 0);
    __syncthreads();
    int cur = 0;
    for (int it = 0; it < 16; ++it) {
        if (it < 15) STAGE_P(cur ^ 1, (it + 1) * 32);
        const _Float16* sAh = &smem[cur][0][0];
        const _Float16* sAl = &smem[cur][1][0];
        const _Float16* sBh = &smem[cur][2][0];
        const _Float16* sBl = &smem[cur][3][0];
        half8v afh[4], afl[4], bfh[4], bfl[4];
#pragma unroll
        for (int tm = 0; tm < 4; ++tm) {
            afh[tm] = *(const half8v*)&sAh[rbA + tm * 512];
            afl[tm] = *(const half8v*)&sAl[rbA + tm * 512];
        }
#pragma unroll
        for (int tn = 0; tn < 4; ++tn) {
            bfh[tn] = *(const half8v*)&sBh[rbB + tn * 512];
            bfl[tn] = *(const half8v*)&sBl[rbB + tn * 512];
        }
#pragma unroll
        for (int tm = 0; tm < 4; ++tm)
#pragma unroll
            for (int tn = 0; tn < 4; ++tn) {
                acch[tm][tn] = __builtin_amdgcn_mfma_f32_16x16x32_f16(afh[tm], bfh[tn], acch[tm][tn], 0, 0, 0);
                accx[tm][tn] = __builtin_amdgcn_mfma_f32_16x16x32_f16(afh[tm], bfl[tn], accx[tm][tn], 0, 0, 0);
                accx[tm][tn] = __builtin_amdgcn_mfma_f32_16x16x32_f16(afl[tm], bfh[tn], accx[tm][tn], 0, 0, 0);
            }
        __syncthreads();
        cur ^= 1;
    }
#undef STAGE_P
#pragma unroll
    for (int tm = 0; tm < 4; ++tm)
#pragma unroll
        for (int reg = 0; reg < 4; ++reg) {
            int m = m0 + wm * 64 + tm * 16 + quad * 4 + reg;
            if (m < M) {
#pragma unroll
                for (int tn = 0; tn < 4; ++tn) {
                    int n = n0 + wn * 64 + tn * 16 + l15;
                    u[(size_t)m * 1536 + n] = acch[tm][tn][reg] + accx[tm][tn][reg] * (1.0f / 4096.0f);
                }
            }
        }
}

// combine (s<=128): resid = rsrc - (0.5*h + 0.5*(conv+bias)); h = lerp(embed[idx]),
// conv[t] = sum_tap lerp of u[.][tap] at t' = t+tap-1 ; rsrc = x at si=0
__global__ __launch_bounds__(256) void k_combine(const float* __restrict__ u,
        const float* __restrict__ embed, const unsigned long long* __restrict__ minbuf,
        const float* __restrict__ bias, const float* __restrict__ rsrc,
        float* __restrict__ resid, int s, float scale) {
    int tid = threadIdx.x;
    int m = blockIdx.x * 2 + (tid >> 7);
    int d4 = (tid & 127) << 2;
    int b = m >> 9, t = m & 511;
    int bs = b * s;
    float4 bi = *(const float4*)(bias + d4);
    float uu = ((float)t + 0.5f) * scale - 0.5f;
    float fl = floorf(uu);
    float w = uu - fl;
    int i0 = (int)fl, i1 = i0 + 1;
    i0 = min(max(i0, 0), s - 1);
    i1 = min(max(i1, 0), s - 1);
    int c0 = (int)(unsigned)minbuf[bs + i0];
    int c1 = (int)(unsigned)minbuf[bs + i1];
    float4 e0 = *(const float4*)(embed + (size_t)c0 * 512 + d4);
    float4 e1 = *(const float4*)(embed + (size_t)c1 * 512 + d4);
    float om = 1.0f - w;
    float4 h4;
    h4.x = om * e0.x + w * e1.x; h4.y = om * e0.y + w * e1.y;
    h4.z = om * e0.z + w * e1.z; h4.w = om * e0.w + w * e1.w;
    float4 conv = make_float4(0.f, 0.f, 0.f, 0.f);
#pragma unroll
    for (int tap = 0; tap < 3; ++tap) {
        int tt = t + tap - 1;
        if (tt >= 0 && tt < 512) {
            float uu2 = ((float)tt + 0.5f) * scale - 0.5f;
            float fl2 = floorf(uu2);
            float w2 = uu2 - fl2;
            int j0 = (int)fl2, j1 = j0 + 1;
            j0 = min(max(j0, 0), s - 1);
            j1 = min(max(j1, 0), s - 1);
            float4 a4 = *(const float4*)(u + (size_t)(bs + j0) * 1536 + tap * 512 + d4);
            float4 b4 = *(const float4*)(u + (size_t)(bs + j1) * 1536 + tap * 512 + d4);
            float ow = 1.0f - w2;
            conv.x += ow * a4.x + w2 * b4.x;
            conv.y += ow * a4.y + w2 * b4.y;
            conv.z += ow * a4.z + w2 * b4.z;
            conv.w += ow * a4.w + w2 * b4.w;
        }
    }
    size_t off = (size_t)m * 512 + d4;
    float4 rv = *(const float4*)(rsrc + off);
    rv.x -= 0.5f * h4.x + 0.5f * (conv.x + bi.x);
    rv.y -= 0.5f * h4.y + 0.5f * (conv.y + bi.y);
    rv.z -= 0.5f * h4.z + 0.5f * (conv.z + bi.z);
    rv.w -= 0.5f * h4.w + 0.5f * (conv.w + bi.w);
    *(float4*)(resid + off) = rv;
}

// q[b,t] = lerp(embed[c0],embed[c1],w) -> split qh/ql (8192 rows x 512)
__global__ __launch_bounds__(256) void k_prep_q(const float* __restrict__ embed,
        const unsigned long long* __restrict__ minbuf, _Float16* __restrict__ qh,
        _Float16* __restrict__ ql, int s, float scale, _Float16* __restrict__ zbuf) {
    int gid = blockIdx.x * 256 + threadIdx.x;   // 524288 threads, 8 halves each
    if (gid < 32) zbuf[gid] = (_Float16)0.f;    // 64B zero row (idempotent)
    int d8 = (gid & 63) << 3;
    int m = gid >> 6;          // b*512 + t
    int b = m >> 9, t = m & 511;
    int bs = b * s;
    float uu = ((float)t + 0.5f) * scale - 0.5f;
    float fl = floorf(uu);
    float w = uu - fl;
    int i0 = (int)fl, i1 = i0 + 1;
    i0 = min(max(i0, 0), s - 1);
    i1 = min(max(i1, 0), s - 1);
    int c0 = (int)(unsigned)minbuf[bs + i0];
    int c1 = (int)(unsigned)minbuf[bs + i1];
    const float* p0 = embed + (size_t)c0 * 512 + d8;
    const float* p1 = embed + (size_t)c1 * 512 + d8;
    float ow = 1.0f - w;
    half8v hh8, ll8;
#pragma unroll
    for (int q = 0; q < 8; ++q) {
        float v = ow * p0[q] + w * p1[q];
        HL hl = split2(v);
        hh8[q] = hl.h; ll8[q] = hl.l;
    }
    *(half8v*)(qh + (size_t)m * 512 + d8) = hh8;
    *(half8v*)(ql + (size_t)m * 512 + d8) = ll8;
}

// direct conv (s in {256,512}): GEMM [8192 x 1536(tap,din)] x [1536 x 512(dout)]
__global__ __launch_bounds__(256, 4) void k_conv(const _Float16* __restrict__ qh,
        const _Float16* __restrict__ ql, const float* __restrict__ embed,
        const _Float16* __restrict__ wh, const _Float16* __restrict__ wl,
        const float* __restrict__ bias, const unsigned long long* __restrict__ minbuf,
        float* __restrict__ resid, int s, float scale,
        const float* __restrict__ x, float* __restrict__ out, int last,
        const _Float16* __restrict__ zbuf) {
    __shared__ _Float16 smem[2][4][2048] __attribute__((aligned(16))); // 32 KB
    int tid = threadIdx.x;
    int lane = tid & 63, wave = tid >> 6;
    int wm = wave >> 1, wn = wave & 1;
    int quad = lane >> 4, l15 = lane & 15;
    int m0 = blockIdx.x * 64, n0 = blockIdx.y * 64;
    int b = m0 >> 9, t0 = m0 & 511;
    int row = wave * 16 + (lane >> 2);
    int slot = lane & 3;
    int ssw = (slot ^ ((row >> 1) & 3)) << 3;   // swizzled source col (halves)
    int ld = wave * 512;                         // dest: wave-uniform + lane*16B

#define STG_C(buf, itv) do { \
    int tap_ = (itv) >> 4; \
    int dk_ = ((itv) & 15) << 5; \
    int tp_ = t0 + row + tap_ - 1; \
    bool v_ = ((unsigned)tp_ < 512u); \
    size_t ao_ = ((size_t)((b << 9) + (v_ ? tp_ : 0)) << 9) + dk_ + ssw; \
    const _Float16* aH_ = v_ ? qh + ao_ : zbuf + ssw; \
    const _Float16* aL_ = v_ ? ql + ao_ : zbuf + ssw; \
    size_t bo_ = ((size_t)((tap_ << 9) + n0 + row) << 9) + dk_ + ssw; \
    gl2lds16(aH_, &smem[buf][0][ld]); \
    gl2lds16(aL_, &smem[buf][1][ld]); \
    gl2lds16(wh + bo_, &smem[buf][2][ld]); \
    gl2lds16(wl + bo_, &smem[buf][3][ld]); \
} while (0)

    floatx4 acch[2][2], accx[2][2];
#pragma unroll
    for (int i = 0; i < 2; ++i)
#pragma unroll
        for (int j = 0; j < 2; ++j)
#pragma unroll
            for (int r = 0; r < 4; ++r) { acch[i][j][r] = 0.f; accx[i][j][r] = 0.f; }

    STG_C(0, 0);
    __syncthreads();
    int cur = 0;
    for (int it = 0; it < 48; ++it) {
        if (it < 47) STG_C(cur ^ 1, it + 1);
        const _Float16* sAh = &smem[cur][0][0];
        const _Float16* sAl = &smem[cur][1][0];
        const _Float16* sBh = &smem[cur][2][0];
        const _Float16* sBl = &smem[cur][3][0];
        half8v afh[2], afl[2], bfh[2], bfl[2];
#pragma unroll
        for (int tm = 0; tm < 2; ++tm) {
            int rA = wm * 32 + tm * 16 + l15;
            int cs = (quad ^ ((rA >> 1) & 3)) << 3;
            afh[tm] = *(const half8v*)&sAh[rA * 32 + cs];
            afl[tm] = *(const half8v*)&sAl[rA * 32 + cs];
        }
#pragma unroll
        for (int tn = 0; tn < 2; ++tn) {
            int rB = wn * 32 + tn * 16 + l15;
            int cs = (quad ^ ((rB >> 1) & 3)) << 3;
            bfh[tn] = *(const half8v*)&sBh[rB * 32 + cs];
            bfl[tn] = *(const half8v*)&sBl[rB * 32 + cs];
        }
#pragma unroll
        for (int tm = 0; tm < 2; ++tm)
#pragma unroll
            for (int tn = 0; tn < 2; ++tn) {
                acch[tm][tn] = __builtin_amdgcn_mfma_f32_16x16x32_f16(afh[tm], bfh[tn], acch[tm][tn], 0, 0, 0);
                accx[tm][tn] = __builtin_amdgcn_mfma_f32_16x16x32_f16(afh[tm], bfl[tn], accx[tm][tn], 0, 0, 0);
                accx[tm][tn] = __builtin_amdgcn_mfma_f32_16x16x32_f16(afl[tm], bfh[tn], accx[tm][tn], 0, 0, 0);
            }
        __syncthreads();
        cur ^= 1;
    }
#undef STG_C
#pragma unroll
    for (int tm = 0; tm < 2; ++tm)
#pragma unroll
        for (int reg = 0; reg < 4; ++reg) {
            int rrow = wm * 32 + tm * 16 + quad * 4 + reg;
            int m = m0 + rrow;
            int t = t0 + rrow;
            float uu = ((float)t + 0.5f) * scale - 0.5f;
            float fl = floorf(uu);
            float w = uu - fl;
            int i0 = (int)fl, i1 = i0 + 1;
            i0 = min(max(i0, 0), s - 1);
            i1 = min(max(i1, 0), s - 1);
            int bs = b * s;
            int c0 = (int)(unsigned)minbuf[bs + i0];
            int c1 = (int)(unsigned)minbuf[bs + i1];
            float ow = 1.0f - w;
#pragma unroll
            for (int tn = 0; tn < 2; ++tn) {
                int n = n0 + wn * 32 + tn * 16 + l15;
                float h = ow * embed[(size_t)c0 * 512 + n] + w * embed[(size_t)c1 * 512 + n];
                float val = acch[tm][tn][reg] + accx[tm][tn][reg] * (1.0f / 4096.0f);
                size_t off = (size_t)m * 512 + n;
                float r2 = resid[off] - (0.5f * h + 0.5f * (val + bias[n]));
                if (last) out[off] = x[off] - r2;
                else resid[off] = r2;
            }
        }
}

extern "C" void kernel_launch(void* const* d_in, const int* in_sizes, int n_in,
                              void* d_out, int out_size, void* d_ws, size_t ws_size,
                              hipStream_t stream) {
    const float* x     = (const float*)d_in[0];
    const float* embed = (const float*)d_in[1];
    const float* pw    = (const float*)d_in[2];
    const float* pb    = (const float*)d_in[3];
    float* out = (float*)d_out;

    // ws layout (floats), ~56.2 MB total:
    // resid 16MB | U 16MB (zh/zl = qh/ql halves; u<=12.6MB aliases after refine) |
    // ehi/elo 8MB | Wt2 hi/lo 12MB | esq 16KB | minbuf 64KB | bm2 4MB | zbuf 64B
    float* resid = (float*)d_ws;
    float* Ubase = resid + 4194304;
    _Float16* zh = (_Float16*)Ubase;            // also qh after refine (s>=256)
    _Float16* zl = zh + 4194304;                // also ql
    float* u = Ubase;
    _Float16* ehi = (_Float16*)(Ubase + 4194304);
    _Float16* elo = ehi + 2097152;
    _Float16* whi = elo + 2097152;
    _Float16* wlo = whi + 3145728;
    float* esq = (float*)(wlo + 3145728);
    unsigned long long* minbuf = (unsigned long long*)(esq + 4096);
    unsigned long long* bm2 = (unsigned long long*)(minbuf + 8192);
    _Float16* zbuf = (_Float16*)(bm2 + 524288);

    k_esq<<<1024, 256, 0, stream>>>(embed, esq);
    k_split_embed<<<2048, 256, 0, stream>>>(embed, ehi, elo);
    k_split_w<<<12288, 256, 0, stream>>>(pw, whi, wlo);

    const int SCv[10] = {1, 2, 4, 8, 16, 32, 64, 128, 256, 512};
    // PHI_IDX with float64-ulp tie-breaks at si=2 and si=7 (verified round 2)
    const int PIv[10] = {0, 0, 1, 1, 1, 2, 2, 3, 3, 3};
    for (int si = 0; si < 10; ++si) {
        int s = SCv[si];
        int M = 16 * s;
        int kp = PIv[si];
        int lg = __builtin_ctz((unsigned)s);
        float scale = (float)s / 512.0f;
        const float* src = (si == 0) ? x : resid;
        k_zmean<<<(M * 512) / 256, 256, 0, stream>>>(src, zh, zl, s, lg);
        k_dist1<<<dim3((M + 127) / 128, 32), 256, 0, stream>>>(zh, ehi, esq, bm2, M);
        k_refine<<<(M + 3) / 4, 256, 0, stream>>>(zh, zl, embed, bm2, minbuf, M);
        if (s <= 128) {
            k_phi<<<dim3((M + 127) / 128, 12), 256, 0, stream>>>(ehi, elo,
                    whi + (size_t)kp * 1536 * 512, wlo + (size_t)kp * 1536 * 512, minbuf, u, M);
            k_combine<<<4096, 256, 0, stream>>>(u, embed, minbuf, pb + kp * 512, src, resid, s, scale);
        } else {
            k_prep_q<<<2048, 256, 0, stream>>>(embed, minbuf, zh, zl, s, scale, zbuf);
            k_conv<<<dim3(128, 8), 256, 0, stream>>>(zh, zl, embed,
                    whi + (size_t)kp * 1536 * 512, wlo + (size_t)kp * 1536 * 512,
                    pb + kp * 512, minbuf, resid, s, scale, x, out, si == 9 ? 1 : 0, zbuf);
        }
    }
}